// Round 9
// baseline (202.350 us; speedup 1.0000x reference)
//
#include <hip/hip_runtime.h>

typedef unsigned short u16;
typedef unsigned int u32;
typedef short short8 __attribute__((ext_vector_type(8)));
typedef short short4v __attribute__((ext_vector_type(4)));
typedef float f32x4 __attribute__((ext_vector_type(4)));

#define EPS 1e-3f
#define C1F 0.18033688011112042f   // 0.125 * log2(e), folded into wk/bk in prep

#if defined(__HIP_DEVICE_COMPILE__)
#define MFMA16(a, b, c) __builtin_amdgcn_mfma_f32_16x16x16bf16_1k(a, b, c, 0, 0, 0)
#else
#define MFMA16(a, b, c) (c)
#endif

static __device__ __forceinline__ u16 f2bf(float f) {
    u32 u = __float_as_uint(f);
    u += 0x7fffu + ((u >> 16) & 1u);   // round-to-nearest-even
    return (u16)(u >> 16);
}
static __device__ __forceinline__ float bf2f(u16 v) {
    u32 u = (u32)v << 16;
    return __uint_as_float(u);
}
// truncation pack (P in [0,1], trunc error <0.4% rel — fine for softmax weights)
static __device__ __forceinline__ u32 pack_bf2_trunc(float a, float b) {
    return __builtin_amdgcn_perm(__float_as_uint(b), __float_as_uint(a), 0x07060302u);
}
static __device__ __forceinline__ void async_cp16(const void* g, void* l) {
    __builtin_amdgcn_global_load_lds(
        (const __attribute__((address_space(1))) unsigned int*)g,
        (__attribute__((address_space(3))) unsigned int*)l, 16, 0, 0);
}

// ---------------------------------------------------------------------------
// prep + bn1 merged. Blocks [0,2048): bn1(x)->h bf16. Blocks [2048,5125):
// weight transposes (coalesced reads), bqkv, bn sc/sh.
// ---------------------------------------------------------------------------
__global__ void prep_bn1_kernel(const float* __restrict__ x,
                            const float* __restrict__ wq, const float* __restrict__ wk,
                            const float* __restrict__ wv, const float* __restrict__ wo,
                            const float* __restrict__ w1, const float* __restrict__ w2,
                            const float* __restrict__ bq, const float* __restrict__ bk,
                            const float* __restrict__ bv,
                            const float* __restrict__ g1, const float* __restrict__ b1,
                            const float* __restrict__ m1, const float* __restrict__ v1,
                            const float* __restrict__ g2, const float* __restrict__ b2,
                            const float* __restrict__ m2, const float* __restrict__ v2,
                            u16* __restrict__ h,
                            u16* __restrict__ wqkvT, u16* __restrict__ woT,
                            u16* __restrict__ w1T, u16* __restrict__ w2T,
                            float* __restrict__ bqkv,
                            float* __restrict__ bn1sc, float* __restrict__ bn1sh,
                            float* __restrict__ bn2sc, float* __restrict__ bn2sh) {
    int bid = blockIdx.x;
    if (bid < 2048) {                         // bn1 part
        int idx = bid * 256 + threadIdx.x;
        int base = idx * 4;
        int c = base & 255;
        float4 xv = *(const float4*)(x + base);
        ushort4 pk;
        {
            float sc0 = g1[c] * rsqrtf(v1[c] + EPS);
            pk.x = f2bf(fmaf(xv.x, sc0, b1[c] - m1[c] * sc0));
            float sc1 = g1[c+1] * rsqrtf(v1[c+1] + EPS);
            pk.y = f2bf(fmaf(xv.y, sc1, b1[c+1] - m1[c+1] * sc1));
            float sc2 = g1[c+2] * rsqrtf(v1[c+2] + EPS);
            pk.z = f2bf(fmaf(xv.z, sc2, b1[c+2] - m1[c+2] * sc2));
            float sc3 = g1[c+3] * rsqrtf(v1[c+3] + EPS);
            pk.w = f2bf(fmaf(xv.w, sc3, b1[c+3] - m1[c+3] * sc3));
        }
        *(ushort4*)(h + base) = pk;
        return;
    }
    int idx = (bid - 2048) * 256 + threadIdx.x;
    if (idx < 196608) {                       // wqkvT [768][256]
        int sec = idx >> 16;                  // 0=q, 1=k, 2=v
        int i = idx & 65535;
        int k = i >> 8, n = i & 255;
        const float* w = sec == 0 ? wq : (sec == 1 ? wk : wv);
        float v = w[i];                       // coalesced: w[k*256+n]
        if (sec == 1) v *= C1F;
        wqkvT[(sec * 256 + n) * 256 + k] = f2bf(v);
    } else if (idx < 262144) {                // woT [256][256]
        int i = idx - 196608; int k = i >> 8, n = i & 255;
        woT[n * 256 + k] = f2bf(wo[i]);
    } else if (idx < 524288) {                // w1T [1024][256]
        int i = idx - 262144; int k = i >> 10, n = i & 1023;
        w1T[n * 256 + k] = f2bf(w1[i]);
    } else if (idx < 786432) {                // w2T [256][1024]
        int i = idx - 524288; int k = i >> 8, n = i & 255;
        w2T[n * 1024 + k] = f2bf(w2[i]);
    } else if (idx < 787200) {                // bqkv [768]
        int i = idx - 786432;
        bqkv[i] = (i < 256) ? bq[i] : (i < 512 ? bk[i - 256] * C1F : bv[i - 512]);
    } else if (idx < 787456) {                // bn1 sc/sh (kept for O-proj epilogue symmetry)
        int i = idx - 787200;
        float sc = g1[i] * rsqrtf(v1[i] + EPS);
        bn1sc[i] = sc; bn1sh[i] = b1[i] - m1[i] * sc;
    } else if (idx < 787712) {                // bn2 sc/sh
        int i = idx - 787456;
        float sc = g2[i] * rsqrtf(v2[i] + EPS);
        bn2sc[i] = sc; bn2sh[i] = b2[i] - m2[i] * sc;
    }
}

// ---------------------------------------------------------------------------
// 64x64-tile double-buffered GEMM (R7 structure, unchanged).
// EPI 0: qkv (col<512: +bias->row-major; col>=512: +bias->vT transposed)
// EPI 1: +bias+resid->f32 x1 AND bn2->bf16 h2
// ---------------------------------------------------------------------------
template <int EPI>
__global__ __launch_bounds__(256) void gemm64(
        const u16* __restrict__ A, const u16* __restrict__ Bt,
        int M, int N, int K,
        const float* __restrict__ bias, const float* __restrict__ resid,
        float* __restrict__ out_f32, u16* __restrict__ out_bf,
        u16* __restrict__ out_vt,
        const float* __restrict__ b2sc, const float* __restrict__ b2sh) {
    __shared__ u16 abuf[2][4096];
    __shared__ u16 bbuf[2][4096];
    const int t = threadIdx.x;
    const int w = t >> 6, lane = t & 63;
    const int l = lane & 15, Q = lane >> 4;
    const int m0 = blockIdx.x * 64;
    const int n0 = blockIdx.y * 64;

    f32x4 acc[4];
#pragma unroll
    for (int nt = 0; nt < 4; ++nt) acc[nt] = (f32x4){0.f, 0.f, 0.f, 0.f};

    auto stage = [&](int k0, int b) {
#pragma unroll
        for (int j = 0; j < 2; ++j) {
            int idx = j * 256 + t;
            int r = idx >> 3, c8 = idx & 7;
            int sc = c8 ^ (r & 7);
            async_cp16(A + (size_t)(m0 + r) * K + k0 + sc * 8, abuf[b] + idx * 8);
        }
#pragma unroll
        for (int j = 0; j < 2; ++j) {
            int idx = j * 256 + t;
            int r = idx >> 3, c8 = idx & 7;
            int sc = c8 ^ (r & 7);
            async_cp16(Bt + (size_t)(n0 + r) * K + k0 + sc * 8, bbuf[b] + idx * 8);
        }
    };

    const int nit = K >> 6;
    stage(0, 0);
    for (int i = 0; i < nit; ++i) {
        __syncthreads();
        if (i + 1 < nit) stage((i + 1) << 6, (i + 1) & 1);
        const u16* ab = abuf[i & 1];
        const u16* bb = bbuf[i & 1];
#pragma unroll
        for (int kd = 0; kd < 2; ++kd) {
            int ar = w * 16 + l;
            short8 afr = *(const short8*)(ab + ar * 64 + (((kd * 4 + Q) ^ (ar & 7))) * 8);
#pragma unroll
            for (int nt = 0; nt < 4; ++nt) {
                int r = nt * 16 + l;
                short8 bfr = *(const short8*)(bb + r * 64 + (((kd * 4 + Q) ^ (r & 7))) * 8);
                acc[nt] = __builtin_amdgcn_mfma_f32_16x16x32_bf16(afr, bfr, acc[nt], 0, 0, 0);
            }
        }
    }

#pragma unroll
    for (int nt = 0; nt < 4; ++nt) {
        int col = n0 + nt * 16 + l;
        int row0 = m0 + w * 16 + Q * 4;
        if (EPI == 0) {
            float b = bias[col];
            if (col < 512) {
#pragma unroll
                for (int r = 0; r < 4; ++r)
                    out_bf[(size_t)(row0 + r) * 512 + col] = f2bf(acc[nt][r] + b);
            } else {
                ushort4 pk;
                pk.x = f2bf(acc[nt][0] + b);
                pk.y = f2bf(acc[nt][1] + b);
                pk.z = f2bf(acc[nt][2] + b);
                pk.w = f2bf(acc[nt][3] + b);
                *(ushort4*)(out_vt + (size_t)(col - 512) * 8192 + row0) = pk;
            }
        } else {
#pragma unroll
            for (int r = 0; r < 4; ++r) {
                int row = row0 + r;
                float val = acc[nt][r];
                size_t oidx = (size_t)row * N + col;
                val += bias[col] + resid[oidx];
                out_f32[oidx] = val;
                out_bf[oidx] = f2bf(fmaf(val, b2sc[col], b2sh[col]));
            }
        }
    }
}

// ---------------------------------------------------------------------------
// Fused FFN: one WG per 32 rows. Phase A: gelu(h2 @ w1) -> gl (LDS, swizzled).
// Phase B: gl @ w2 + x1 -> out (f32). Weights double-buffered via
// global_load_lds; gbuf never touches HBM.
// LDS: h2t 16KB + gl 64KB + wbuf 64KB = 144KB (1 WG/CU).
// ---------------------------------------------------------------------------
__global__ __launch_bounds__(256) void ffn_fused(
        const u16* __restrict__ h2, const u16* __restrict__ w1T,
        const u16* __restrict__ w2T, const float* __restrict__ x1,
        float* __restrict__ out) {
    __shared__ u16 h2t[32 * 256];     // 16 KB
    __shared__ u16 gl[32 * 1024];     // 64 KB, chunk-XOR swizzle per row
    __shared__ u16 wbuf[2][64 * 256]; // 64 KB (phase B views as [256][64])
    const int t = threadIdx.x;
    const int w = t >> 6, lane = t & 63;
    const int l = lane & 15, Q = lane >> 4;
    const int m0 = blockIdx.x * 32;

    // stage h2 tile (32x256) + w1 chunk 0
#pragma unroll
    for (int j = 0; j < 4; ++j) {
        int idx = j * 256 + t;
        int r = idx >> 5, c = idx & 31;
        int sc = (c & 24) | ((c & 7) ^ (r & 7));
        async_cp16(h2 + (size_t)(m0 + r) * 256 + sc * 8, h2t + idx * 8);
    }
#pragma unroll
    for (int j = 0; j < 8; ++j) {
        int idx = j * 256 + t;
        int r = idx >> 5, c = idx & 31;
        int sc = (c & 24) | ((c & 7) ^ (r & 7));
        async_cp16(w1T + (size_t)r * 256 + sc * 8, wbuf[0] + idx * 8);
    }

    // ---- phase A: 16 chunks of 64 ffn-cols
    for (int c0 = 0; c0 < 16; ++c0) {
        __syncthreads();   // drains prefetch; tiles ready
        if (c0 < 15) {
#pragma unroll
            for (int j = 0; j < 8; ++j) {
                int idx = j * 256 + t;
                int r = idx >> 5, c = idx & 31;
                int sc = (c & 24) | ((c & 7) ^ (r & 7));
                async_cp16(w1T + (size_t)((c0 + 1) * 64 + r) * 256 + sc * 8,
                           wbuf[(c0 + 1) & 1] + idx * 8);
            }
        } else {           // prefetch w2 chunk 0 into buf 0
#pragma unroll
            for (int j = 0; j < 8; ++j) {
                int idx = j * 256 + t;
                int r = idx >> 3, c = idx & 7;
                int sc = c ^ (r & 7);
                async_cp16(w2T + (size_t)r * 1024 + sc * 8, wbuf[0] + idx * 8);
            }
        }
        const u16* wb = wbuf[c0 & 1];
        f32x4 acc[2];
        acc[0] = (f32x4){0.f, 0.f, 0.f, 0.f};
        acc[1] = (f32x4){0.f, 0.f, 0.f, 0.f};
#pragma unroll
        for (int kd = 0; kd < 8; ++kd) {
            int ch = kd * 4 + Q;
            int rB = w * 16 + l;
            short8 bfr = *(const short8*)(wb + rB * 256 + ((ch & 24) | ((ch & 7) ^ (rB & 7))) * 8);
#pragma unroll
            for (int mt = 0; mt < 2; ++mt) {
                int rA = mt * 16 + l;
                short8 afr = *(const short8*)(h2t + rA * 256 + ((ch & 24) | ((ch & 7) ^ (rA & 7))) * 8);
                acc[mt] = __builtin_amdgcn_mfma_f32_16x16x32_bf16(afr, bfr, acc[mt], 0, 0, 0);
            }
        }
        // gelu -> gl (swizzled scalar writes)
#pragma unroll
        for (int mt = 0; mt < 2; ++mt)
#pragma unroll
            for (int r = 0; r < 4; ++r) {
                int row = mt * 16 + Q * 4 + r;
                int k = c0 * 64 + w * 16 + l;
                float v = acc[mt][r];
                float g = 0.5f * v * (1.f + erff(v * 0.70710678118654752f));
                int chunki = k >> 3;
                int swz = (chunki & ~7) | ((chunki & 7) ^ (row & 7));
                gl[row * 1024 + swz * 8 + (k & 7)] = f2bf(g);
            }
    }

    // ---- phase B: 16 chunks of 64 k; acc2 persists
    f32x4 acc2[2][4];
#pragma unroll
    for (int mt = 0; mt < 2; ++mt)
#pragma unroll
        for (int nt = 0; nt < 4; ++nt) acc2[mt][nt] = (f32x4){0.f, 0.f, 0.f, 0.f};

    for (int c2 = 0; c2 < 16; ++c2) {
        __syncthreads();   // drains prefetch; gl complete (first iter)
        if (c2 < 15) {
#pragma unroll
            for (int j = 0; j < 8; ++j) {
                int idx = j * 256 + t;
                int r = idx >> 3, c = idx & 7;
                int sc = c ^ (r & 7);
                async_cp16(w2T + (size_t)r * 1024 + (c2 + 1) * 64 + sc * 8,
                           wbuf[(c2 + 1) & 1] + idx * 8);
            }
        }
        const u16* wb = wbuf[c2 & 1];
#pragma unroll
        for (int kd = 0; kd < 2; ++kd) {
            short8 afr[2];
#pragma unroll
            for (int mt = 0; mt < 2; ++mt) {
                int rA = mt * 16 + l;
                int chunki = c2 * 8 + kd * 4 + Q;
                int swz = (chunki & ~7) | ((chunki & 7) ^ (rA & 7));
                afr[mt] = *(const short8*)(gl + rA * 1024 + swz * 8);
            }
#pragma unroll
            for (int nt = 0; nt < 4; ++nt) {
                int rB = w * 64 + nt * 16 + l;
                int ch = kd * 4 + Q;
                short8 bfr = *(const short8*)(wb + rB * 64 + (ch ^ (rB & 7)) * 8);
#pragma unroll
                for (int mt = 0; mt < 2; ++mt)
                    acc2[mt][nt] = __builtin_amdgcn_mfma_f32_16x16x32_bf16(afr[mt], bfr, acc2[mt][nt], 0, 0, 0);
            }
        }
    }

    // epilogue: + x1 -> out f32
#pragma unroll
    for (int mt = 0; mt < 2; ++mt)
#pragma unroll
        for (int nt = 0; nt < 4; ++nt)
#pragma unroll
            for (int r = 0; r < 4; ++r) {
                int row = m0 + mt * 16 + Q * 4 + r;
                int col = w * 64 + nt * 16 + l;
                size_t oidx = (size_t)row * 256 + col;
                out[oidx] = acc2[mt][nt][r] + x1[oidx];
            }
}

// ---------------------------------------------------------------------------
// Flash attention (R6 v5 + micro: no fmin, trunc pack). Single-buffered
// 16 KB K/V LDS; grid (16 qt, 16 bh, 8 sp); 256 thr; bf16 partials.
// ---------------------------------------------------------------------------
static __device__ __forceinline__ void stage_tiles(const u16* kglob, const u16* vglob,
                                                   u16* kdst, u16* vdst,
                                                   int w, int lane, int kt) {
#pragma unroll
    for (int j = 0; j < 2; ++j) {
        int cw = (w * 2 + j) * 64 + lane;     // chunk 0..511
        int r = cw >> 3;                       // tile row 0..63
        int c = (cw & 7) ^ (r & 7);            // swizzled source chunk
        async_cp16(kglob + ((size_t)(kt * 64 + r)) * 512 + c * 8, kdst + (w * 2 + j) * 512);
        async_cp16(vglob + ((size_t)r) * 8192 + kt * 64 + c * 8, vdst + (w * 2 + j) * 512);
    }
}

__global__ __launch_bounds__(256) void attn_kernel(const u16* __restrict__ qk,
                                                   const u16* __restrict__ vT,
                                                   u16* __restrict__ opart,
                                                   float* __restrict__ lpart) {
    __shared__ u16 kbuf[4096];
    __shared__ u16 vbuf[4096];
    const int t = threadIdx.x;
    const int w = t >> 6, lane = t & 63;
    const int l = lane & 15, Q = lane >> 4;
    const int qt = blockIdx.x;        // 0..15
    const int bh = blockIdx.y;        // 0..15
    const int sp = blockIdx.z;        // 0..7 (256 s each)
    const int bb = bh >> 2, hd = bh & 3;
    const size_t rowbase = (size_t)bb * 2048;
    const int q0 = qt * 128 + w * 32;

    short8 qf[2][2];
#pragma unroll
    for (int qg = 0; qg < 2; ++qg)
#pragma unroll
        for (int kd = 0; kd < 2; ++kd)
            qf[qg][kd] = *(const short8*)(qk + (rowbase + q0 + qg * 16 + l) * 512
                                          + hd * 64 + kd * 32 + Q * 8);

    f32x4 o[2][4];
#pragma unroll
    for (int qg = 0; qg < 2; ++qg)
#pragma unroll
        for (int dt = 0; dt < 4; ++dt) o[qg][dt] = (f32x4){0.f, 0.f, 0.f, 0.f};
    float lacc[2] = {0.f, 0.f};

    const u16* kglob = qk + (rowbase + sp * 256) * 512 + 256 + hd * 64;
    const u16* vglob = vT + ((size_t)(hd * 64)) * 8192 + rowbase + sp * 256;

    for (int kt = 0; kt < 4; ++kt) {
        stage_tiles(kglob, vglob, kbuf, vbuf, w, lane, kt);
        __syncthreads();

        union { u32 u[2]; short4v s4; } pf[2][4];
#pragma unroll
        for (int st = 0; st < 4; ++st) {
            int r = st * 16 + l;
            short8 kf0 = *(const short8*)(kbuf + r * 64 + ((Q) ^ (r & 7)) * 8);
            short8 kf1 = *(const short8*)(kbuf + r * 64 + ((4 + Q) ^ (r & 7)) * 8);
#pragma unroll
            for (int qg = 0; qg < 2; ++qg) {
                f32x4 s = (f32x4){0.f, 0.f, 0.f, 0.f};
                s = __builtin_amdgcn_mfma_f32_16x16x32_bf16(kf0, qf[qg][0], s, 0, 0, 0);
                s = __builtin_amdgcn_mfma_f32_16x16x32_bf16(kf1, qf[qg][1], s, 0, 0, 0);
                float p0 = exp2f(s[0]);
                float p1 = exp2f(s[1]);
                float p2 = exp2f(s[2]);
                float p3 = exp2f(s[3]);
                lacc[qg] += (p0 + p1) + (p2 + p3);
                pf[qg][st].u[0] = pack_bf2_trunc(p0, p1);
                pf[qg][st].u[1] = pack_bf2_trunc(p2, p3);
            }
        }

#pragma unroll
        for (int c = 0; c < 4; ++c) {
#pragma unroll
            for (int dt = 0; dt < 4; ++dt) {
                int r = dt * 16 + l;
                int slot = (2 * c + (Q >> 1)) ^ (r & 7);
                short4v vf = *(const short4v*)(vbuf + r * 64 + slot * 8 + (Q & 1) * 4);
                o[0][dt] = MFMA16(vf, pf[0][c].s4, o[0][dt]);
                o[1][dt] = MFMA16(vf, pf[1][c].s4, o[1][dt]);
            }
        }
        __syncthreads();
    }

#pragma unroll
    for (int qg = 0; qg < 2; ++qg) {
        float v = lacc[qg];
        v += __shfl_xor(v, 16);
        v += __shfl_xor(v, 32);
        lacc[qg] = v;
    }
    u16* ob = opart + (((size_t)sp * 16 + bh) * 2048 + q0) * 64;
#pragma unroll
    for (int qg = 0; qg < 2; ++qg)
#pragma unroll
        for (int dt = 0; dt < 4; ++dt) {
            ushort4 pk;
            pk.x = f2bf(o[qg][dt][0]);
            pk.y = f2bf(o[qg][dt][1]);
            pk.z = f2bf(o[qg][dt][2]);
            pk.w = f2bf(o[qg][dt][3]);
            *(ushort4*)(ob + (size_t)(qg * 16 + l) * 64 + dt * 16 + Q * 4) = pk;
        }
    if (Q == 0) {
        size_t lb = ((size_t)sp * 16 + bh) * 2048 + q0;
        lpart[lb + l] = lacc[0];
        lpart[lb + 16 + l] = lacc[1];
    }
}

// ---------------------------------------------------------------------------
// combine: ctx[b*2048+s][h*64+d] = sum_sp(o_sp) / sum_sp(l_sp) -> bf16
// ---------------------------------------------------------------------------
__global__ void combine_kernel(const u16* __restrict__ opart,
                               const float* __restrict__ lpart,
                               u16* __restrict__ ctx) {
    int idx = blockIdx.x * 256 + threadIdx.x;
    int e = idx * 4;
    int row = e >> 8, col = e & 255;
    int b = row >> 11, s = row & 2047, h = col >> 6, d = col & 63;
    float a0 = 0.f, a1 = 0.f, a2 = 0.f, a3 = 0.f, lsum = 0.f;
#pragma unroll
    for (int sp = 0; sp < 8; ++sp) {
        size_t pb = (((size_t)sp * 16 + b * 4 + h) * 2048 + s) * 64 + d;
        ushort4 ov = *(const ushort4*)(opart + pb);
        a0 += bf2f(ov.x); a1 += bf2f(ov.y); a2 += bf2f(ov.z); a3 += bf2f(ov.w);
        lsum += lpart[((size_t)sp * 16 + b * 4 + h) * 2048 + s];
    }
    float li = 1.0f / lsum;
    ushort4 pk;
    pk.x = f2bf(a0 * li);
    pk.y = f2bf(a1 * li);
    pk.z = f2bf(a2 * li);
    pk.w = f2bf(a3 * li);
    *(ushort4*)(ctx + e) = pk;
}

// ---------------------------------------------------------------------------
extern "C" void kernel_launch(void* const* d_in, const int* in_sizes, int n_in,
                              void* d_out, int out_size, void* d_ws, size_t ws_size,
                              hipStream_t stream) {
    (void)in_sizes; (void)n_in; (void)out_size; (void)ws_size;
    const float* x  = (const float*)d_in[0];
    const float* g1 = (const float*)d_in[1];
    const float* b1 = (const float*)d_in[2];
    const float* m1 = (const float*)d_in[3];
    const float* v1 = (const float*)d_in[4];
    const float* wq = (const float*)d_in[5];
    const float* bq = (const float*)d_in[6];
    const float* wk = (const float*)d_in[7];
    const float* bk = (const float*)d_in[8];
    const float* wv = (const float*)d_in[9];
    const float* bv = (const float*)d_in[10];
    const float* wo = (const float*)d_in[11];
    const float* bo = (const float*)d_in[12];
    const float* g2 = (const float*)d_in[13];
    const float* b2 = (const float*)d_in[14];
    const float* m2 = (const float*)d_in[15];
    const float* v2 = (const float*)d_in[16];
    const float* w1 = (const float*)d_in[17];
    const float* w2 = (const float*)d_in[18];

    char* ws = (char*)d_ws;
    u16*   qkb    = (u16*)(ws + (0ull << 20));    // [8192][512] bf16, 8 MB
    u16*   vTb    = (u16*)(ws + (8ull << 20));    // [256][8192] bf16, 4 MB
    u16*   h_buf  = (u16*)(ws + (12ull << 20));   // [8192][256] bf16, 4 MB
    u16*   ctx    = (u16*)(ws + (16ull << 20));   // [8192][256] bf16, 4 MB
    float* x1     = (float*)(ws + (20ull << 20)); // [8192][256] f32, 8 MB
    u16*   h2     = (u16*)(ws + (28ull << 20));   // [8192][256] bf16, 4 MB
    u16*   opart  = (u16*)(ws + (48ull << 20));   // [8][16][2048][64] bf16, 32 MB
    float* lpart  = (float*)(ws + (80ull << 20)); // [8][16][2048] f32, 1 MB
    u16*   wqkvT  = (u16*)(ws + (81ull << 20));   // [768][256] bf16
    u16*   woT    = (u16*)(ws + (82ull << 20));   // [256][256]
    u16*   w1T    = (u16*)(ws + (83ull << 20));   // [1024][256]
    u16*   w2T    = (u16*)(ws + (84ull << 20));   // [256][1024]
    float* bqkv   = (float*)(ws + (85ull << 20)); // [768]
    float* bn1sc  = (float*)(ws + (85ull << 20) + 4096);
    float* bn1sh  = (float*)(ws + (85ull << 20) + 8192);
    float* bn2sc  = (float*)(ws + (85ull << 20) + 12288);
    float* bn2sh  = (float*)(ws + (85ull << 20) + 16384);
    float* out    = (float*)d_out;

    prep_bn1_kernel<<<5125, 256, 0, stream>>>(x, wq, wk, wv, wo, w1, w2, bq, bk, bv,
                                              g1, b1, m1, v1, g2, b2, m2, v2,
                                              h_buf, wqkvT, woT, w1T, w2T, bqkv,
                                              bn1sc, bn1sh, bn2sc, bn2sh);
    // QKV projection (q|k row-major into qkb; v transposed into vTb)
    gemm64<0><<<dim3(128, 12), 256, 0, stream>>>(
        h_buf, wqkvT, 8192, 768, 256, bqkv, nullptr, nullptr, qkb, vTb, nullptr, nullptr);
    // attention partials + combine
    attn_kernel<<<dim3(16, 16, 8), 256, 0, stream>>>(qkb, vTb, opart, lpart);
    combine_kernel<<<2048, 256, 0, stream>>>(opart, lpart, ctx);
    // O projection + residual + bn2
    gemm64<1><<<dim3(128, 4), 256, 0, stream>>>(
        ctx, woT, 8192, 256, 256, bo, x, x1, h2, nullptr, bn2sc, bn2sh);
    // fused FFN (gelu intermediate stays in LDS) -> out
    ffn_fused<<<256, 256, 0, stream>>>(h2, w1T, w2T, x1, out);
}

// Round 10
// 187.661 us; speedup vs baseline: 1.0783x; 1.0783x over previous
//
#include <hip/hip_runtime.h>

typedef unsigned short u16;
typedef unsigned int u32;
typedef short short8 __attribute__((ext_vector_type(8)));
typedef short short4v __attribute__((ext_vector_type(4)));
typedef float f32x4 __attribute__((ext_vector_type(4)));

#define EPS 1e-3f
#define C1F 0.18033688011112042f   // 0.125 * log2(e), folded into wk/bk in prep

#if defined(__HIP_DEVICE_COMPILE__)
#define MFMA16(a, b, c) __builtin_amdgcn_mfma_f32_16x16x16bf16_1k(a, b, c, 0, 0, 0)
#else
#define MFMA16(a, b, c) (c)
#endif

static __device__ __forceinline__ u16 f2bf(float f) {
    u32 u = __float_as_uint(f);
    u += 0x7fffu + ((u >> 16) & 1u);   // round-to-nearest-even
    return (u16)(u >> 16);
}
static __device__ __forceinline__ float bf2f(u16 v) {
    u32 u = (u32)v << 16;
    return __uint_as_float(u);
}
// truncation pack (P in [0,1], trunc error <0.4% rel — fine for softmax weights)
static __device__ __forceinline__ u32 pack_bf2_trunc(float a, float b) {
    return __builtin_amdgcn_perm(__float_as_uint(b), __float_as_uint(a), 0x07060302u);
}
static __device__ __forceinline__ void async_cp16(const void* g, void* l) {
    __builtin_amdgcn_global_load_lds(
        (const __attribute__((address_space(1))) unsigned int*)g,
        (__attribute__((address_space(3))) unsigned int*)l, 16, 0, 0);
}

// ---------------------------------------------------------------------------
// prep + bn1 merged. Blocks [0,2048): bn1(x)->h bf16. Blocks [2048,5125):
// weight transposes (coalesced reads), bqkv, bn sc/sh.
// ---------------------------------------------------------------------------
__global__ void prep_bn1_kernel(const float* __restrict__ x,
                            const float* __restrict__ wq, const float* __restrict__ wk,
                            const float* __restrict__ wv, const float* __restrict__ wo,
                            const float* __restrict__ w1, const float* __restrict__ w2,
                            const float* __restrict__ bq, const float* __restrict__ bk,
                            const float* __restrict__ bv,
                            const float* __restrict__ g1, const float* __restrict__ b1,
                            const float* __restrict__ m1, const float* __restrict__ v1,
                            const float* __restrict__ g2, const float* __restrict__ b2,
                            const float* __restrict__ m2, const float* __restrict__ v2,
                            u16* __restrict__ h,
                            u16* __restrict__ wqkvT, u16* __restrict__ woT,
                            u16* __restrict__ w1T, u16* __restrict__ w2T,
                            float* __restrict__ bqkv,
                            float* __restrict__ bn2sc, float* __restrict__ bn2sh) {
    int bid = blockIdx.x;
    if (bid < 2048) {                         // bn1 part
        int idx = bid * 256 + threadIdx.x;
        int base = idx * 4;
        int c = base & 255;
        float4 xv = *(const float4*)(x + base);
        ushort4 pk;
        {
            float sc0 = g1[c] * rsqrtf(v1[c] + EPS);
            pk.x = f2bf(fmaf(xv.x, sc0, b1[c] - m1[c] * sc0));
            float sc1 = g1[c+1] * rsqrtf(v1[c+1] + EPS);
            pk.y = f2bf(fmaf(xv.y, sc1, b1[c+1] - m1[c+1] * sc1));
            float sc2 = g1[c+2] * rsqrtf(v1[c+2] + EPS);
            pk.z = f2bf(fmaf(xv.z, sc2, b1[c+2] - m1[c+2] * sc2));
            float sc3 = g1[c+3] * rsqrtf(v1[c+3] + EPS);
            pk.w = f2bf(fmaf(xv.w, sc3, b1[c+3] - m1[c+3] * sc3));
        }
        *(ushort4*)(h + base) = pk;
        return;
    }
    int idx = (bid - 2048) * 256 + threadIdx.x;
    if (idx < 196608) {                       // wqkvT [768][256]
        int sec = idx >> 16;                  // 0=q, 1=k, 2=v
        int i = idx & 65535;
        int k = i >> 8, n = i & 255;
        const float* w = sec == 0 ? wq : (sec == 1 ? wk : wv);
        float v = w[i];                       // coalesced: w[k*256+n]
        if (sec == 1) v *= C1F;
        wqkvT[(sec * 256 + n) * 256 + k] = f2bf(v);
    } else if (idx < 262144) {                // woT [256][256]
        int i = idx - 196608; int k = i >> 8, n = i & 255;
        woT[n * 256 + k] = f2bf(wo[i]);
    } else if (idx < 524288) {                // w1T [1024][256]
        int i = idx - 262144; int k = i >> 10, n = i & 1023;
        w1T[n * 256 + k] = f2bf(w1[i]);
    } else if (idx < 786432) {                // w2T [256][1024]
        int i = idx - 524288; int k = i >> 8, n = i & 255;
        w2T[n * 1024 + k] = f2bf(w2[i]);
    } else if (idx < 787200) {                // bqkv [768]
        int i = idx - 786432;
        bqkv[i] = (i < 256) ? bq[i] : (i < 512 ? bk[i - 256] * C1F : bv[i - 512]);
    } else if (idx < 787456) {                // bn2 sc/sh
        int i = idx - 787200;
        float sc = g2[i] * rsqrtf(v2[i] + EPS);
        bn2sc[i] = sc; bn2sh[i] = b2[i] - m2[i] * sc;
    }
}

// ---------------------------------------------------------------------------
// 64x64-tile double-buffered GEMM (R7 structure — best measured).
// EPI 0: qkv (col<512: +bias->row-major; col>=512: +bias->vT transposed)
// EPI 1: +bias+resid->f32 x1 AND bn2->bf16 h2
// EPI 2: gelu->bf16 | EPI 3: +resid->f32
// ---------------------------------------------------------------------------
template <int EPI>
__global__ __launch_bounds__(256) void gemm64(
        const u16* __restrict__ A, const u16* __restrict__ Bt,
        int M, int N, int K,
        const float* __restrict__ bias, const float* __restrict__ resid,
        float* __restrict__ out_f32, u16* __restrict__ out_bf,
        u16* __restrict__ out_vt,
        const float* __restrict__ b2sc, const float* __restrict__ b2sh) {
    __shared__ u16 abuf[2][4096];
    __shared__ u16 bbuf[2][4096];
    const int t = threadIdx.x;
    const int w = t >> 6, lane = t & 63;
    const int l = lane & 15, Q = lane >> 4;
    const int m0 = blockIdx.x * 64;
    const int n0 = blockIdx.y * 64;

    f32x4 acc[4];
#pragma unroll
    for (int nt = 0; nt < 4; ++nt) acc[nt] = (f32x4){0.f, 0.f, 0.f, 0.f};

    auto stage = [&](int k0, int b) {
#pragma unroll
        for (int j = 0; j < 2; ++j) {
            int idx = j * 256 + t;
            int r = idx >> 3, c8 = idx & 7;
            int sc = c8 ^ (r & 7);
            async_cp16(A + (size_t)(m0 + r) * K + k0 + sc * 8, abuf[b] + idx * 8);
        }
#pragma unroll
        for (int j = 0; j < 2; ++j) {
            int idx = j * 256 + t;
            int r = idx >> 3, c8 = idx & 7;
            int sc = c8 ^ (r & 7);
            async_cp16(Bt + (size_t)(n0 + r) * K + k0 + sc * 8, bbuf[b] + idx * 8);
        }
    };

    const int nit = K >> 6;
    stage(0, 0);
    for (int i = 0; i < nit; ++i) {
        __syncthreads();              // vmcnt drained: tile i ready
        if (i + 1 < nit) stage((i + 1) << 6, (i + 1) & 1);
        const u16* ab = abuf[i & 1];
        const u16* bb = bbuf[i & 1];
#pragma unroll
        for (int kd = 0; kd < 2; ++kd) {
            int ar = w * 16 + l;
            short8 afr = *(const short8*)(ab + ar * 64 + (((kd * 4 + Q) ^ (ar & 7))) * 8);
#pragma unroll
            for (int nt = 0; nt < 4; ++nt) {
                int r = nt * 16 + l;
                short8 bfr = *(const short8*)(bb + r * 64 + (((kd * 4 + Q) ^ (r & 7))) * 8);
                acc[nt] = __builtin_amdgcn_mfma_f32_16x16x32_bf16(afr, bfr, acc[nt], 0, 0, 0);
            }
        }
    }

#pragma unroll
    for (int nt = 0; nt < 4; ++nt) {
        int col = n0 + nt * 16 + l;
        int row0 = m0 + w * 16 + Q * 4;
        if (EPI == 0) {
            float b = bias[col];
            if (col < 512) {
#pragma unroll
                for (int r = 0; r < 4; ++r)
                    out_bf[(size_t)(row0 + r) * 512 + col] = f2bf(acc[nt][r] + b);
            } else {
                ushort4 pk;
                pk.x = f2bf(acc[nt][0] + b);
                pk.y = f2bf(acc[nt][1] + b);
                pk.z = f2bf(acc[nt][2] + b);
                pk.w = f2bf(acc[nt][3] + b);
                *(ushort4*)(out_vt + (size_t)(col - 512) * 8192 + row0) = pk;
            }
        } else {
#pragma unroll
            for (int r = 0; r < 4; ++r) {
                int row = row0 + r;
                float val = acc[nt][r];
                size_t oidx = (size_t)row * N + col;
                if (EPI == 1) {
                    val += bias[col] + resid[oidx];
                    out_f32[oidx] = val;
                    out_bf[oidx] = f2bf(fmaf(val, b2sc[col], b2sh[col]));
                } else if (EPI == 2) {
                    float gl = 0.5f * val * (1.f + erff(val * 0.70710678118654752f));
                    out_bf[oidx] = f2bf(gl);
                } else {
                    out_f32[oidx] = val + resid[oidx];
                }
            }
        }
    }
}

// ---------------------------------------------------------------------------
// Flash attention (R6 structure + R9 micro: no clamp, trunc pack).
// Single-buffered 16 KB K/V LDS; grid (16 qt, 16 bh, 8 sp); 256 thr.
// ---------------------------------------------------------------------------
static __device__ __forceinline__ void stage_tiles(const u16* kglob, const u16* vglob,
                                                   u16* kdst, u16* vdst,
                                                   int w, int lane, int kt) {
#pragma unroll
    for (int j = 0; j < 2; ++j) {
        int cw = (w * 2 + j) * 64 + lane;     // chunk 0..511
        int r = cw >> 3;                       // tile row 0..63
        int c = (cw & 7) ^ (r & 7);            // swizzled source chunk
        async_cp16(kglob + ((size_t)(kt * 64 + r)) * 512 + c * 8, kdst + (w * 2 + j) * 512);
        async_cp16(vglob + ((size_t)r) * 8192 + kt * 64 + c * 8, vdst + (w * 2 + j) * 512);
    }
}

__global__ __launch_bounds__(256) void attn_kernel(const u16* __restrict__ qk,
                                                   const u16* __restrict__ vT,
                                                   u16* __restrict__ opart,
                                                   float* __restrict__ lpart) {
    __shared__ u16 kbuf[4096];
    __shared__ u16 vbuf[4096];
    const int t = threadIdx.x;
    const int w = t >> 6, lane = t & 63;
    const int l = lane & 15, Q = lane >> 4;
    const int qt = blockIdx.x;        // 0..15
    const int bh = blockIdx.y;        // 0..15
    const int sp = blockIdx.z;        // 0..7 (256 s each)
    const int bb = bh >> 2, hd = bh & 3;
    const size_t rowbase = (size_t)bb * 2048;
    const int q0 = qt * 128 + w * 32;

    short8 qf[2][2];
#pragma unroll
    for (int qg = 0; qg < 2; ++qg)
#pragma unroll
        for (int kd = 0; kd < 2; ++kd)
            qf[qg][kd] = *(const short8*)(qk + (rowbase + q0 + qg * 16 + l) * 512
                                          + hd * 64 + kd * 32 + Q * 8);

    f32x4 o[2][4];
#pragma unroll
    for (int qg = 0; qg < 2; ++qg)
#pragma unroll
        for (int dt = 0; dt < 4; ++dt) o[qg][dt] = (f32x4){0.f, 0.f, 0.f, 0.f};
    float lacc[2] = {0.f, 0.f};

    const u16* kglob = qk + (rowbase + sp * 256) * 512 + 256 + hd * 64;
    const u16* vglob = vT + ((size_t)(hd * 64)) * 8192 + rowbase + sp * 256;

    for (int kt = 0; kt < 4; ++kt) {
        stage_tiles(kglob, vglob, kbuf, vbuf, w, lane, kt);
        __syncthreads();

        union { u32 u[2]; short4v s4; } pf[2][4];
#pragma unroll
        for (int st = 0; st < 4; ++st) {
            int r = st * 16 + l;
            short8 kf0 = *(const short8*)(kbuf + r * 64 + ((Q) ^ (r & 7)) * 8);
            short8 kf1 = *(const short8*)(kbuf + r * 64 + ((4 + Q) ^ (r & 7)) * 8);
#pragma unroll
            for (int qg = 0; qg < 2; ++qg) {
                f32x4 s = (f32x4){0.f, 0.f, 0.f, 0.f};
                s = __builtin_amdgcn_mfma_f32_16x16x32_bf16(kf0, qf[qg][0], s, 0, 0, 0);
                s = __builtin_amdgcn_mfma_f32_16x16x32_bf16(kf1, qf[qg][1], s, 0, 0, 0);
                float p0 = exp2f(s[0]);
                float p1 = exp2f(s[1]);
                float p2 = exp2f(s[2]);
                float p3 = exp2f(s[3]);
                lacc[qg] += (p0 + p1) + (p2 + p3);
                pf[qg][st].u[0] = pack_bf2_trunc(p0, p1);
                pf[qg][st].u[1] = pack_bf2_trunc(p2, p3);
            }
        }

#pragma unroll
        for (int c = 0; c < 4; ++c) {
#pragma unroll
            for (int dt = 0; dt < 4; ++dt) {
                int r = dt * 16 + l;
                int slot = (2 * c + (Q >> 1)) ^ (r & 7);
                short4v vf = *(const short4v*)(vbuf + r * 64 + slot * 8 + (Q & 1) * 4);
                o[0][dt] = MFMA16(vf, pf[0][c].s4, o[0][dt]);
                o[1][dt] = MFMA16(vf, pf[1][c].s4, o[1][dt]);
            }
        }
        __syncthreads();
    }

#pragma unroll
    for (int qg = 0; qg < 2; ++qg) {
        float v = lacc[qg];
        v += __shfl_xor(v, 16);
        v += __shfl_xor(v, 32);
        lacc[qg] = v;
    }
    u16* ob = opart + (((size_t)sp * 16 + bh) * 2048 + q0) * 64;
#pragma unroll
    for (int qg = 0; qg < 2; ++qg)
#pragma unroll
        for (int dt = 0; dt < 4; ++dt) {
            ushort4 pk;
            pk.x = f2bf(o[qg][dt][0]);
            pk.y = f2bf(o[qg][dt][1]);
            pk.z = f2bf(o[qg][dt][2]);
            pk.w = f2bf(o[qg][dt][3]);
            *(ushort4*)(ob + (size_t)(qg * 16 + l) * 64 + dt * 16 + Q * 4) = pk;
        }
    if (Q == 0) {
        size_t lb = ((size_t)sp * 16 + bh) * 2048 + q0;
        lpart[lb + l] = lacc[0];
        lpart[lb + 16 + l] = lacc[1];
    }
}

// ---------------------------------------------------------------------------
// combine: ctx[b*2048+s][h*64+d] = sum_sp(o_sp) / sum_sp(l_sp) -> bf16
// ---------------------------------------------------------------------------
__global__ void combine_kernel(const u16* __restrict__ opart,
                               const float* __restrict__ lpart,
                               u16* __restrict__ ctx) {
    int idx = blockIdx.x * 256 + threadIdx.x;
    int e = idx * 4;
    int row = e >> 8, col = e & 255;
    int b = row >> 11, s = row & 2047, h = col >> 6, d = col & 63;
    float a0 = 0.f, a1 = 0.f, a2 = 0.f, a3 = 0.f, lsum = 0.f;
#pragma unroll
    for (int sp = 0; sp < 8; ++sp) {
        size_t pb = (((size_t)sp * 16 + b * 4 + h) * 2048 + s) * 64 + d;
        ushort4 ov = *(const ushort4*)(opart + pb);
        a0 += bf2f(ov.x); a1 += bf2f(ov.y); a2 += bf2f(ov.z); a3 += bf2f(ov.w);
        lsum += lpart[((size_t)sp * 16 + b * 4 + h) * 2048 + s];
    }
    float li = 1.0f / lsum;
    ushort4 pk;
    pk.x = f2bf(a0 * li);
    pk.y = f2bf(a1 * li);
    pk.z = f2bf(a2 * li);
    pk.w = f2bf(a3 * li);
    *(ushort4*)(ctx + e) = pk;
}

// ---------------------------------------------------------------------------
extern "C" void kernel_launch(void* const* d_in, const int* in_sizes, int n_in,
                              void* d_out, int out_size, void* d_ws, size_t ws_size,
                              hipStream_t stream) {
    (void)in_sizes; (void)n_in; (void)out_size; (void)ws_size;
    const float* x  = (const float*)d_in[0];
    const float* g1 = (const float*)d_in[1];
    const float* b1 = (const float*)d_in[2];
    const float* m1 = (const float*)d_in[3];
    const float* v1 = (const float*)d_in[4];
    const float* wq = (const float*)d_in[5];
    const float* bq = (const float*)d_in[6];
    const float* wk = (const float*)d_in[7];
    const float* bk = (const float*)d_in[8];
    const float* wv = (const float*)d_in[9];
    const float* bv = (const float*)d_in[10];
    const float* wo = (const float*)d_in[11];
    const float* bo = (const float*)d_in[12];
    const float* g2 = (const float*)d_in[13];
    const float* b2 = (const float*)d_in[14];
    const float* m2 = (const float*)d_in[15];
    const float* v2 = (const float*)d_in[16];
    const float* w1 = (const float*)d_in[17];
    const float* w2 = (const float*)d_in[18];

    char* ws = (char*)d_ws;
    u16*   qkb    = (u16*)(ws + (0ull << 20));    // [8192][512] bf16, 8 MB
    u16*   vTb    = (u16*)(ws + (8ull << 20));    // [256][8192] bf16, 4 MB
    u16*   h_buf  = (u16*)(ws + (12ull << 20));   // [8192][256] bf16, 4 MB
    u16*   ctx    = (u16*)(ws + (16ull << 20));   // [8192][256] bf16, 4 MB
    float* x1     = (float*)(ws + (20ull << 20)); // [8192][256] f32, 8 MB
    u16*   h2     = (u16*)(ws + (28ull << 20));   // [8192][256] bf16, 4 MB
    u16*   gbuf   = (u16*)(ws + (32ull << 20));   // [8192][1024] bf16, 16 MB
    u16*   opart  = (u16*)(ws + (48ull << 20));   // [8][16][2048][64] bf16, 32 MB
    float* lpart  = (float*)(ws + (80ull << 20)); // [8][16][2048] f32, 1 MB
    u16*   wqkvT  = (u16*)(ws + (81ull << 20));   // [768][256] bf16
    u16*   woT    = (u16*)(ws + (82ull << 20));   // [256][256]
    u16*   w1T    = (u16*)(ws + (83ull << 20));   // [1024][256]
    u16*   w2T    = (u16*)(ws + (84ull << 20));   // [256][1024]
    float* bqkv   = (float*)(ws + (85ull << 20)); // [768]
    float* bn2sc  = (float*)(ws + (85ull << 20) + 4096);
    float* bn2sh  = (float*)(ws + (85ull << 20) + 8192);
    float* out    = (float*)d_out;

    prep_bn1_kernel<<<5125, 256, 0, stream>>>(x, wq, wk, wv, wo, w1, w2, bq, bk, bv,
                                              g1, b1, m1, v1, g2, b2, m2, v2,
                                              h_buf, wqkvT, woT, w1T, w2T, bqkv,
                                              bn2sc, bn2sh);
    // QKV projection (q|k row-major into qkb; v transposed into vTb)
    gemm64<0><<<dim3(128, 12), 256, 0, stream>>>(
        h_buf, wqkvT, 8192, 768, 256, bqkv, nullptr, nullptr, qkb, vTb, nullptr, nullptr);
    // attention partials + combine
    attn_kernel<<<dim3(16, 16, 8), 256, 0, stream>>>(qkb, vTb, opart, lpart);
    combine_kernel<<<2048, 256, 0, stream>>>(opart, lpart, ctx);
    // O projection + residual + bn2
    gemm64<1><<<dim3(128, 4), 256, 0, stream>>>(
        ctx, woT, 8192, 256, 256, bo, x, x1, h2, nullptr, bn2sc, bn2sh);
    // FFN1 + gelu
    gemm64<2><<<dim3(128, 16), 256, 0, stream>>>(
        h2, w1T, 8192, 1024, 256, nullptr, nullptr, nullptr, gbuf, nullptr, nullptr, nullptr);
    // FFN2 + residual -> out
    gemm64<3><<<dim3(128, 4), 256, 0, stream>>>(
        gbuf, w2T, 8192, 256, 1024, nullptr, x1, out, nullptr, nullptr, nullptr, nullptr);
}

// Round 11
// 186.131 us; speedup vs baseline: 1.0871x; 1.0082x over previous
//
#include <hip/hip_runtime.h>

typedef unsigned short u16;
typedef unsigned int u32;
typedef short short8 __attribute__((ext_vector_type(8)));
typedef short short4v __attribute__((ext_vector_type(4)));
typedef float f32x4 __attribute__((ext_vector_type(4)));

#define EPS 1e-3f
#define C1F 0.18033688011112042f   // 0.125 * log2(e), folded into wk/bk in prep

#if defined(__HIP_DEVICE_COMPILE__)
#define MFMA16(a, b, c) __builtin_amdgcn_mfma_f32_16x16x16bf16_1k(a, b, c, 0, 0, 0)
#define EXP2F(x) __builtin_amdgcn_exp2f(x)
#else
#define MFMA16(a, b, c) (c)
#define EXP2F(x) exp2f(x)
#endif

static __device__ __forceinline__ u16 f2bf(float f) {
    u32 u = __float_as_uint(f);
    u += 0x7fffu + ((u >> 16) & 1u);   // round-to-nearest-even
    return (u16)(u >> 16);
}
static __device__ __forceinline__ float bf2f(u16 v) {
    u32 u = (u32)v << 16;
    return __uint_as_float(u);
}
// truncation pack (P in [0,1], trunc error <0.4% rel — fine for softmax weights)
static __device__ __forceinline__ u32 pack_bf2_trunc(float a, float b) {
    return __builtin_amdgcn_perm(__float_as_uint(b), __float_as_uint(a), 0x07060302u);
}
static __device__ __forceinline__ void async_cp16(const void* g, void* l) {
    __builtin_amdgcn_global_load_lds(
        (const __attribute__((address_space(1))) unsigned int*)g,
        (__attribute__((address_space(3))) unsigned int*)l, 16, 0, 0);
}

// ---------------------------------------------------------------------------
// prep + bn1 merged. Blocks [0,2048): bn1(x)->h bf16. Blocks [2048,5125):
// weight transposes (coalesced reads), bqkv, bn sc/sh.
// ---------------------------------------------------------------------------
__global__ void prep_bn1_kernel(const float* __restrict__ x,
                            const float* __restrict__ wq, const float* __restrict__ wk,
                            const float* __restrict__ wv, const float* __restrict__ wo,
                            const float* __restrict__ w1, const float* __restrict__ w2,
                            const float* __restrict__ bq, const float* __restrict__ bk,
                            const float* __restrict__ bv,
                            const float* __restrict__ g1, const float* __restrict__ b1,
                            const float* __restrict__ m1, const float* __restrict__ v1,
                            const float* __restrict__ g2, const float* __restrict__ b2,
                            const float* __restrict__ m2, const float* __restrict__ v2,
                            u16* __restrict__ h,
                            u16* __restrict__ wqkvT, u16* __restrict__ woT,
                            u16* __restrict__ w1T, u16* __restrict__ w2T,
                            float* __restrict__ bqkv,
                            float* __restrict__ bn2sc, float* __restrict__ bn2sh) {
    int bid = blockIdx.x;
    if (bid < 2048) {                         // bn1 part
        int idx = bid * 256 + threadIdx.x;
        int base = idx * 4;
        int c = base & 255;
        float4 xv = *(const float4*)(x + base);
        ushort4 pk;
        {
            float sc0 = g1[c] * rsqrtf(v1[c] + EPS);
            pk.x = f2bf(fmaf(xv.x, sc0, b1[c] - m1[c] * sc0));
            float sc1 = g1[c+1] * rsqrtf(v1[c+1] + EPS);
            pk.y = f2bf(fmaf(xv.y, sc1, b1[c+1] - m1[c+1] * sc1));
            float sc2 = g1[c+2] * rsqrtf(v1[c+2] + EPS);
            pk.z = f2bf(fmaf(xv.z, sc2, b1[c+2] - m1[c+2] * sc2));
            float sc3 = g1[c+3] * rsqrtf(v1[c+3] + EPS);
            pk.w = f2bf(fmaf(xv.w, sc3, b1[c+3] - m1[c+3] * sc3));
        }
        *(ushort4*)(h + base) = pk;
        return;
    }
    int idx = (bid - 2048) * 256 + threadIdx.x;
    if (idx < 196608) {                       // wqkvT [768][256]
        int sec = idx >> 16;                  // 0=q, 1=k, 2=v
        int i = idx & 65535;
        int k = i >> 8, n = i & 255;
        const float* w = sec == 0 ? wq : (sec == 1 ? wk : wv);
        float v = w[i];                       // coalesced: w[k*256+n]
        if (sec == 1) v *= C1F;
        wqkvT[(sec * 256 + n) * 256 + k] = f2bf(v);
    } else if (idx < 262144) {                // woT [256][256]
        int i = idx - 196608; int k = i >> 8, n = i & 255;
        woT[n * 256 + k] = f2bf(wo[i]);
    } else if (idx < 524288) {                // w1T [1024][256]
        int i = idx - 262144; int k = i >> 10, n = i & 1023;
        w1T[n * 256 + k] = f2bf(w1[i]);
    } else if (idx < 786432) {                // w2T [256][1024]
        int i = idx - 524288; int k = i >> 8, n = i & 255;
        w2T[n * 1024 + k] = f2bf(w2[i]);
    } else if (idx < 787200) {                // bqkv [768]
        int i = idx - 786432;
        bqkv[i] = (i < 256) ? bq[i] : (i < 512 ? bk[i - 256] * C1F : bv[i - 512]);
    } else if (idx < 787456) {                // bn2 sc/sh
        int i = idx - 787200;
        float sc = g2[i] * rsqrtf(v2[i] + EPS);
        bn2sc[i] = sc; bn2sh[i] = b2[i] - m2[i] * sc;
    }
}

// ---------------------------------------------------------------------------
// 64x64-tile double-buffered GEMM (R7 structure — best measured).
// EPI 0: qkv (col<512: +bias->row-major; col>=512: +bias->vT transposed)
// EPI 1: +bias+resid->f32 x1 AND bn2->bf16 h2
// EPI 2: gelu->bf16 | EPI 3: +resid->f32
// ---------------------------------------------------------------------------
template <int EPI>
__global__ __launch_bounds__(256) void gemm64(
        const u16* __restrict__ A, const u16* __restrict__ Bt,
        int M, int N, int K,
        const float* __restrict__ bias, const float* __restrict__ resid,
        float* __restrict__ out_f32, u16* __restrict__ out_bf,
        u16* __restrict__ out_vt,
        const float* __restrict__ b2sc, const float* __restrict__ b2sh) {
    __shared__ u16 abuf[2][4096];
    __shared__ u16 bbuf[2][4096];
    const int t = threadIdx.x;
    const int w = t >> 6, lane = t & 63;
    const int l = lane & 15, Q = lane >> 4;
    const int m0 = blockIdx.x * 64;
    const int n0 = blockIdx.y * 64;

    f32x4 acc[4];
#pragma unroll
    for (int nt = 0; nt < 4; ++nt) acc[nt] = (f32x4){0.f, 0.f, 0.f, 0.f};

    auto stage = [&](int k0, int b) {
#pragma unroll
        for (int j = 0; j < 2; ++j) {
            int idx = j * 256 + t;
            int r = idx >> 3, c8 = idx & 7;
            int sc = c8 ^ (r & 7);
            async_cp16(A + (size_t)(m0 + r) * K + k0 + sc * 8, abuf[b] + idx * 8);
        }
#pragma unroll
        for (int j = 0; j < 2; ++j) {
            int idx = j * 256 + t;
            int r = idx >> 3, c8 = idx & 7;
            int sc = c8 ^ (r & 7);
            async_cp16(Bt + (size_t)(n0 + r) * K + k0 + sc * 8, bbuf[b] + idx * 8);
        }
    };

    const int nit = K >> 6;
    stage(0, 0);
    for (int i = 0; i < nit; ++i) {
        __syncthreads();              // vmcnt drained: tile i ready
        if (i + 1 < nit) stage((i + 1) << 6, (i + 1) & 1);
        const u16* ab = abuf[i & 1];
        const u16* bb = bbuf[i & 1];
#pragma unroll
        for (int kd = 0; kd < 2; ++kd) {
            int ar = w * 16 + l;
            short8 afr = *(const short8*)(ab + ar * 64 + (((kd * 4 + Q) ^ (ar & 7))) * 8);
#pragma unroll
            for (int nt = 0; nt < 4; ++nt) {
                int r = nt * 16 + l;
                short8 bfr = *(const short8*)(bb + r * 64 + (((kd * 4 + Q) ^ (r & 7))) * 8);
                acc[nt] = __builtin_amdgcn_mfma_f32_16x16x32_bf16(afr, bfr, acc[nt], 0, 0, 0);
            }
        }
    }

#pragma unroll
    for (int nt = 0; nt < 4; ++nt) {
        int col = n0 + nt * 16 + l;
        int row0 = m0 + w * 16 + Q * 4;
        if (EPI == 0) {
            float b = bias[col];
            if (col < 512) {
#pragma unroll
                for (int r = 0; r < 4; ++r)
                    out_bf[(size_t)(row0 + r) * 512 + col] = f2bf(acc[nt][r] + b);
            } else {
                ushort4 pk;
                pk.x = f2bf(acc[nt][0] + b);
                pk.y = f2bf(acc[nt][1] + b);
                pk.z = f2bf(acc[nt][2] + b);
                pk.w = f2bf(acc[nt][3] + b);
                *(ushort4*)(out_vt + (size_t)(col - 512) * 8192 + row0) = pk;
            }
        } else {
#pragma unroll
            for (int r = 0; r < 4; ++r) {
                int row = row0 + r;
                float val = acc[nt][r];
                size_t oidx = (size_t)row * N + col;
                if (EPI == 1) {
                    val += bias[col] + resid[oidx];
                    out_f32[oidx] = val;
                    out_bf[oidx] = f2bf(fmaf(val, b2sc[col], b2sh[col]));
                } else if (EPI == 2) {
                    float gl = 0.5f * val * (1.f + erff(val * 0.70710678118654752f));
                    out_bf[oidx] = f2bf(gl);
                } else {
                    out_f32[oidx] = val + resid[oidx];
                }
            }
        }
    }
}

// ---------------------------------------------------------------------------
// Flash attention v7: 1D grid blk = qt*128 + sp*16 + bh (qt slowest). Blocks
// round-robin to XCDs by linear index and 128 % 8 == 0, so each XCD sees the
// SAME 16 (sp,bh) K/V chunks at every qt round -> K/V stay L2-resident across
// all 16 qt re-reads. l accumulated via ones-row MFMA (no VALU adds).
// Single-buffered 16 KB K/V LDS; 256 thr; bf16 partials.
// ---------------------------------------------------------------------------
static __device__ __forceinline__ void stage_tiles(const u16* kglob, const u16* vglob,
                                                   u16* kdst, u16* vdst,
                                                   int w, int lane, int kt) {
#pragma unroll
    for (int j = 0; j < 2; ++j) {
        int cw = (w * 2 + j) * 64 + lane;     // chunk 0..511
        int r = cw >> 3;                       // tile row 0..63
        int c = (cw & 7) ^ (r & 7);            // swizzled source chunk
        async_cp16(kglob + ((size_t)(kt * 64 + r)) * 512 + c * 8, kdst + (w * 2 + j) * 512);
        async_cp16(vglob + ((size_t)r) * 8192 + kt * 64 + c * 8, vdst + (w * 2 + j) * 512);
    }
}

__global__ __launch_bounds__(256) void attn_kernel(const u16* __restrict__ qk,
                                                   const u16* __restrict__ vT,
                                                   u16* __restrict__ opart,
                                                   float* __restrict__ lpart) {
    __shared__ u16 kbuf[4096];
    __shared__ u16 vbuf[4096];
    const int t = threadIdx.x;
    const int w = t >> 6, lane = t & 63;
    const int l = lane & 15, Q = lane >> 4;
    const int blk = blockIdx.x;
    const int qt = blk >> 7;          // 0..15  (slowest: XCD-local K/V reuse)
    const int sp = (blk >> 4) & 7;    // 0..7   (256 s each)
    const int bh = blk & 15;          // 0..15
    const int bb = bh >> 2, hd = bh & 3;
    const size_t rowbase = (size_t)bb * 2048;
    const int q0 = qt * 128 + w * 32;

    short8 qf[2][2];
#pragma unroll
    for (int qg = 0; qg < 2; ++qg)
#pragma unroll
        for (int kd = 0; kd < 2; ++kd)
            qf[qg][kd] = *(const short8*)(qk + (rowbase + q0 + qg * 16 + l) * 512
                                          + hd * 64 + kd * 32 + Q * 8);

    f32x4 o[2][4];
#pragma unroll
    for (int qg = 0; qg < 2; ++qg)
#pragma unroll
        for (int dt = 0; dt < 4; ++dt) o[qg][dt] = (f32x4){0.f, 0.f, 0.f, 0.f};
    f32x4 oL[2];                      // l accumulator via ones-MFMA
    oL[0] = (f32x4){0.f, 0.f, 0.f, 0.f};
    oL[1] = (f32x4){0.f, 0.f, 0.f, 0.f};
    union { u32 u[2]; short4v s4; } ones;
    ones.u[0] = 0x3F803F80u; ones.u[1] = 0x3F803F80u;   // bf16 1.0 x4

    const u16* kglob = qk + (rowbase + sp * 256) * 512 + 256 + hd * 64;
    const u16* vglob = vT + ((size_t)(hd * 64)) * 8192 + rowbase + sp * 256;

    for (int kt = 0; kt < 4; ++kt) {
        stage_tiles(kglob, vglob, kbuf, vbuf, w, lane, kt);
        __syncthreads();

        union { u32 u[2]; short4v s4; } pf[2][4];
#pragma unroll
        for (int st = 0; st < 4; ++st) {
            int r = st * 16 + l;
            short8 kf0 = *(const short8*)(kbuf + r * 64 + ((Q) ^ (r & 7)) * 8);
            short8 kf1 = *(const short8*)(kbuf + r * 64 + ((4 + Q) ^ (r & 7)) * 8);
#pragma unroll
            for (int qg = 0; qg < 2; ++qg) {
                f32x4 s = (f32x4){0.f, 0.f, 0.f, 0.f};
                s = __builtin_amdgcn_mfma_f32_16x16x32_bf16(kf0, qf[qg][0], s, 0, 0, 0);
                s = __builtin_amdgcn_mfma_f32_16x16x32_bf16(kf1, qf[qg][1], s, 0, 0, 0);
                float p0 = EXP2F(s[0]);
                float p1 = EXP2F(s[1]);
                float p2 = EXP2F(s[2]);
                float p3 = EXP2F(s[3]);
                pf[qg][st].u[0] = pack_bf2_trunc(p0, p1);
                pf[qg][st].u[1] = pack_bf2_trunc(p2, p3);
            }
        }

#pragma unroll
        for (int c = 0; c < 4; ++c) {
#pragma unroll
            for (int dt = 0; dt < 4; ++dt) {
                int r = dt * 16 + l;
                int slot = (2 * c + (Q >> 1)) ^ (r & 7);
                short4v vf = *(const short4v*)(vbuf + r * 64 + slot * 8 + (Q & 1) * 4);
                o[0][dt] = MFMA16(vf, pf[0][c].s4, o[0][dt]);
                o[1][dt] = MFMA16(vf, pf[1][c].s4, o[1][dt]);
            }
            oL[0] = MFMA16(ones.s4, pf[0][c].s4, oL[0]);
            oL[1] = MFMA16(ones.s4, pf[1][c].s4, oL[1]);
        }
        __syncthreads();
    }

    // epilogue: l = oL[qg][0] (all rows of the ones-product are identical,
    // each col q = lane&15 holds its full sum over this WG's s range)
    u16* ob = opart + (((size_t)sp * 16 + bh) * 2048 + q0) * 64;
#pragma unroll
    for (int qg = 0; qg < 2; ++qg)
#pragma unroll
        for (int dt = 0; dt < 4; ++dt) {
            ushort4 pk;
            pk.x = f2bf(o[qg][dt][0]);
            pk.y = f2bf(o[qg][dt][1]);
            pk.z = f2bf(o[qg][dt][2]);
            pk.w = f2bf(o[qg][dt][3]);
            *(ushort4*)(ob + (size_t)(qg * 16 + l) * 64 + dt * 16 + Q * 4) = pk;
        }
    if (Q == 0) {
        size_t lb = ((size_t)sp * 16 + bh) * 2048 + q0;
        lpart[lb + l] = oL[0][0];
        lpart[lb + 16 + l] = oL[1][0];
    }
}

// ---------------------------------------------------------------------------
// combine: ctx[b*2048+s][h*64+d] = sum_sp(o_sp) / sum_sp(l_sp) -> bf16
// ---------------------------------------------------------------------------
__global__ void combine_kernel(const u16* __restrict__ opart,
                               const float* __restrict__ lpart,
                               u16* __restrict__ ctx) {
    int idx = blockIdx.x * 256 + threadIdx.x;
    int e = idx * 4;
    int row = e >> 8, col = e & 255;
    int b = row >> 11, s = row & 2047, h = col >> 6, d = col & 63;
    float a0 = 0.f, a1 = 0.f, a2 = 0.f, a3 = 0.f, lsum = 0.f;
#pragma unroll
    for (int sp = 0; sp < 8; ++sp) {
        size_t pb = (((size_t)sp * 16 + b * 4 + h) * 2048 + s) * 64 + d;
        ushort4 ov = *(const ushort4*)(opart + pb);
        a0 += bf2f(ov.x); a1 += bf2f(ov.y); a2 += bf2f(ov.z); a3 += bf2f(ov.w);
        lsum += lpart[((size_t)sp * 16 + b * 4 + h) * 2048 + s];
    }
    float li = 1.0f / lsum;
    ushort4 pk;
    pk.x = f2bf(a0 * li);
    pk.y = f2bf(a1 * li);
    pk.z = f2bf(a2 * li);
    pk.w = f2bf(a3 * li);
    *(ushort4*)(ctx + e) = pk;
}

// ---------------------------------------------------------------------------
extern "C" void kernel_launch(void* const* d_in, const int* in_sizes, int n_in,
                              void* d_out, int out_size, void* d_ws, size_t ws_size,
                              hipStream_t stream) {
    (void)in_sizes; (void)n_in; (void)out_size; (void)ws_size;
    const float* x  = (const float*)d_in[0];
    const float* g1 = (const float*)d_in[1];
    const float* b1 = (const float*)d_in[2];
    const float* m1 = (const float*)d_in[3];
    const float* v1 = (const float*)d_in[4];
    const float* wq = (const float*)d_in[5];
    const float* bq = (const float*)d_in[6];
    const float* wk = (const float*)d_in[7];
    const float* bk = (const float*)d_in[8];
    const float* wv = (const float*)d_in[9];
    const float* bv = (const float*)d_in[10];
    const float* wo = (const float*)d_in[11];
    const float* bo = (const float*)d_in[12];
    const float* g2 = (const float*)d_in[13];
    const float* b2 = (const float*)d_in[14];
    const float* m2 = (const float*)d_in[15];
    const float* v2 = (const float*)d_in[16];
    const float* w1 = (const float*)d_in[17];
    const float* w2 = (const float*)d_in[18];

    char* ws = (char*)d_ws;
    u16*   qkb    = (u16*)(ws + (0ull << 20));    // [8192][512] bf16, 8 MB
    u16*   vTb    = (u16*)(ws + (8ull << 20));    // [256][8192] bf16, 4 MB
    u16*   h_buf  = (u16*)(ws + (12ull << 20));   // [8192][256] bf16, 4 MB
    u16*   ctx    = (u16*)(ws + (16ull << 20));   // [8192][256] bf16, 4 MB
    float* x1     = (float*)(ws + (20ull << 20)); // [8192][256] f32, 8 MB
    u16*   h2     = (u16*)(ws + (28ull << 20));   // [8192][256] bf16, 4 MB
    u16*   gbuf   = (u16*)(ws + (32ull << 20));   // [8192][1024] bf16, 16 MB
    u16*   opart  = (u16*)(ws + (48ull << 20));   // [8][16][2048][64] bf16, 32 MB
    float* lpart  = (float*)(ws + (80ull << 20)); // [8][16][2048] f32, 1 MB
    u16*   wqkvT  = (u16*)(ws + (81ull << 20));   // [768][256] bf16
    u16*   woT    = (u16*)(ws + (82ull << 20));   // [256][256]
    u16*   w1T    = (u16*)(ws + (83ull << 20));   // [1024][256]
    u16*   w2T    = (u16*)(ws + (84ull << 20));   // [256][1024]
    float* bqkv   = (float*)(ws + (85ull << 20)); // [768]
    float* bn2sc  = (float*)(ws + (85ull << 20) + 4096);
    float* bn2sh  = (float*)(ws + (85ull << 20) + 8192);
    float* out    = (float*)d_out;

    prep_bn1_kernel<<<5125, 256, 0, stream>>>(x, wq, wk, wv, wo, w1, w2, bq, bk, bv,
                                              g1, b1, m1, v1, g2, b2, m2, v2,
                                              h_buf, wqkvT, woT, w1T, w2T, bqkv,
                                              bn2sc, bn2sh);
    // QKV projection (q|k row-major into qkb; v transposed into vTb)
    gemm64<0><<<dim3(128, 12), 256, 0, stream>>>(
        h_buf, wqkvT, 8192, 768, 256, bqkv, nullptr, nullptr, qkb, vTb, nullptr, nullptr);
    // attention partials (1D grid, qt slowest for XCD L2 reuse) + combine
    attn_kernel<<<2048, 256, 0, stream>>>(qkb, vTb, opart, lpart);
    combine_kernel<<<2048, 256, 0, stream>>>(opart, lpart, ctx);
    // O projection + residual + bn2
    gemm64<1><<<dim3(128, 4), 256, 0, stream>>>(
        ctx, woT, 8192, 256, 256, bo, x, x1, h2, nullptr, bn2sc, bn2sh);
    // FFN1 + gelu
    gemm64<2><<<dim3(128, 16), 256, 0, stream>>>(
        h2, w1T, 8192, 1024, 256, nullptr, nullptr, nullptr, gbuf, nullptr, nullptr, nullptr);
    // FFN2 + residual -> out
    gemm64<3><<<dim3(128, 4), 256, 0, stream>>>(
        gbuf, w2T, 8192, 256, 1024, nullptr, x1, out, nullptr, nullptr, nullptr, nullptr);
}

// Round 12
// 181.205 us; speedup vs baseline: 1.1167x; 1.0272x over previous
//
#include <hip/hip_runtime.h>

typedef unsigned short u16;
typedef unsigned int u32;
typedef short short8 __attribute__((ext_vector_type(8)));
typedef short short4v __attribute__((ext_vector_type(4)));
typedef float f32x4 __attribute__((ext_vector_type(4)));

#define EPS 1e-3f
#define C1F 0.18033688011112042f   // 0.125 * log2(e), folded into wk/bk in prep

#if defined(__HIP_DEVICE_COMPILE__)
#define MFMA16(a, b, c) __builtin_amdgcn_mfma_f32_16x16x16bf16_1k(a, b, c, 0, 0, 0)
#define EXP2F(x) __builtin_amdgcn_exp2f(x)
#else
#define MFMA16(a, b, c) (c)
#define EXP2F(x) exp2f(x)
#endif

static __device__ __forceinline__ u16 f2bf(float f) {
    u32 u = __float_as_uint(f);
    u += 0x7fffu + ((u >> 16) & 1u);   // round-to-nearest-even
    return (u16)(u >> 16);
}
static __device__ __forceinline__ float bf2f(u16 v) {
    u32 u = (u32)v << 16;
    return __uint_as_float(u);
}
// truncation pack (P in [0,1], trunc error <0.4% rel — fine for softmax weights)
static __device__ __forceinline__ u32 pack_bf2_trunc(float a, float b) {
    return __builtin_amdgcn_perm(__float_as_uint(b), __float_as_uint(a), 0x07060302u);
}
static __device__ __forceinline__ void async_cp16(const void* g, void* l) {
    __builtin_amdgcn_global_load_lds(
        (const __attribute__((address_space(1))) unsigned int*)g,
        (__attribute__((address_space(3))) unsigned int*)l, 16, 0, 0);
}

// ---------------------------------------------------------------------------
// prep + bn1 merged. Blocks [0,2048): bn1(x)->h bf16. Blocks [2048,5125):
// weight transposes (coalesced reads), bqkv, bn sc/sh.
// ---------------------------------------------------------------------------
__global__ void prep_bn1_kernel(const float* __restrict__ x,
                            const float* __restrict__ wq, const float* __restrict__ wk,
                            const float* __restrict__ wv, const float* __restrict__ wo,
                            const float* __restrict__ w1, const float* __restrict__ w2,
                            const float* __restrict__ bq, const float* __restrict__ bk,
                            const float* __restrict__ bv,
                            const float* __restrict__ g1, const float* __restrict__ b1,
                            const float* __restrict__ m1, const float* __restrict__ v1,
                            const float* __restrict__ g2, const float* __restrict__ b2,
                            const float* __restrict__ m2, const float* __restrict__ v2,
                            u16* __restrict__ h,
                            u16* __restrict__ wqkvT, u16* __restrict__ woT,
                            u16* __restrict__ w1T, u16* __restrict__ w2T,
                            float* __restrict__ bqkv,
                            float* __restrict__ bn2sc, float* __restrict__ bn2sh) {
    int bid = blockIdx.x;
    if (bid < 2048) {                         // bn1 part
        int idx = bid * 256 + threadIdx.x;
        int base = idx * 4;
        int c = base & 255;
        float4 xv = *(const float4*)(x + base);
        ushort4 pk;
        {
            float sc0 = g1[c] * rsqrtf(v1[c] + EPS);
            pk.x = f2bf(fmaf(xv.x, sc0, b1[c] - m1[c] * sc0));
            float sc1 = g1[c+1] * rsqrtf(v1[c+1] + EPS);
            pk.y = f2bf(fmaf(xv.y, sc1, b1[c+1] - m1[c+1] * sc1));
            float sc2 = g1[c+2] * rsqrtf(v1[c+2] + EPS);
            pk.z = f2bf(fmaf(xv.z, sc2, b1[c+2] - m1[c+2] * sc2));
            float sc3 = g1[c+3] * rsqrtf(v1[c+3] + EPS);
            pk.w = f2bf(fmaf(xv.w, sc3, b1[c+3] - m1[c+3] * sc3));
        }
        *(ushort4*)(h + base) = pk;
        return;
    }
    int idx = (bid - 2048) * 256 + threadIdx.x;
    if (idx < 196608) {                       // wqkvT [768][256]
        int sec = idx >> 16;                  // 0=q, 1=k, 2=v
        int i = idx & 65535;
        int k = i >> 8, n = i & 255;
        const float* w = sec == 0 ? wq : (sec == 1 ? wk : wv);
        float v = w[i];                       // coalesced: w[k*256+n]
        if (sec == 1) v *= C1F;
        wqkvT[(sec * 256 + n) * 256 + k] = f2bf(v);
    } else if (idx < 262144) {                // woT [256][256]
        int i = idx - 196608; int k = i >> 8, n = i & 255;
        woT[n * 256 + k] = f2bf(wo[i]);
    } else if (idx < 524288) {                // w1T [1024][256]
        int i = idx - 262144; int k = i >> 10, n = i & 1023;
        w1T[n * 256 + k] = f2bf(w1[i]);
    } else if (idx < 786432) {                // w2T [256][1024]
        int i = idx - 524288; int k = i >> 8, n = i & 255;
        w2T[n * 1024 + k] = f2bf(w2[i]);
    } else if (idx < 787200) {                // bqkv [768]
        int i = idx - 786432;
        bqkv[i] = (i < 256) ? bq[i] : (i < 512 ? bk[i - 256] * C1F : bv[i - 512]);
    } else if (idx < 787456) {                // bn2 sc/sh
        int i = idx - 787200;
        float sc = g2[i] * rsqrtf(v2[i] + EPS);
        bn2sc[i] = sc; bn2sh[i] = b2[i] - m2[i] * sc;
    }
}

// ---------------------------------------------------------------------------
// 64x64-tile double-buffered GEMM (R7 structure — best measured).
// EPI 0: qkv (col<512: +bias->row-major; col>=512: +bias->vT transposed)
// EPI 1: +bias+resid->f32 x1 AND bn2->bf16 h2
// EPI 2: gelu->bf16 | EPI 3: +resid->f32
// ---------------------------------------------------------------------------
template <int EPI>
__global__ __launch_bounds__(256) void gemm64(
        const u16* __restrict__ A, const u16* __restrict__ Bt,
        int M, int N, int K,
        const float* __restrict__ bias, const float* __restrict__ resid,
        float* __restrict__ out_f32, u16* __restrict__ out_bf,
        u16* __restrict__ out_vt,
        const float* __restrict__ b2sc, const float* __restrict__ b2sh) {
    __shared__ u16 abuf[2][4096];
    __shared__ u16 bbuf[2][4096];
    const int t = threadIdx.x;
    const int w = t >> 6, lane = t & 63;
    const int l = lane & 15, Q = lane >> 4;
    const int m0 = blockIdx.x * 64;
    const int n0 = blockIdx.y * 64;

    f32x4 acc[4];
#pragma unroll
    for (int nt = 0; nt < 4; ++nt) acc[nt] = (f32x4){0.f, 0.f, 0.f, 0.f};

    auto stage = [&](int k0, int b) {
#pragma unroll
        for (int j = 0; j < 2; ++j) {
            int idx = j * 256 + t;
            int r = idx >> 3, c8 = idx & 7;
            int sc = c8 ^ (r & 7);
            async_cp16(A + (size_t)(m0 + r) * K + k0 + sc * 8, abuf[b] + idx * 8);
        }
#pragma unroll
        for (int j = 0; j < 2; ++j) {
            int idx = j * 256 + t;
            int r = idx >> 3, c8 = idx & 7;
            int sc = c8 ^ (r & 7);
            async_cp16(Bt + (size_t)(n0 + r) * K + k0 + sc * 8, bbuf[b] + idx * 8);
        }
    };

    const int nit = K >> 6;
    stage(0, 0);
    for (int i = 0; i < nit; ++i) {
        __syncthreads();              // vmcnt drained: tile i ready
        if (i + 1 < nit) stage((i + 1) << 6, (i + 1) & 1);
        const u16* ab = abuf[i & 1];
        const u16* bb = bbuf[i & 1];
#pragma unroll
        for (int kd = 0; kd < 2; ++kd) {
            int ar = w * 16 + l;
            short8 afr = *(const short8*)(ab + ar * 64 + (((kd * 4 + Q) ^ (ar & 7))) * 8);
#pragma unroll
            for (int nt = 0; nt < 4; ++nt) {
                int r = nt * 16 + l;
                short8 bfr = *(const short8*)(bb + r * 64 + (((kd * 4 + Q) ^ (r & 7))) * 8);
                acc[nt] = __builtin_amdgcn_mfma_f32_16x16x32_bf16(afr, bfr, acc[nt], 0, 0, 0);
            }
        }
    }

#pragma unroll
    for (int nt = 0; nt < 4; ++nt) {
        int col = n0 + nt * 16 + l;
        int row0 = m0 + w * 16 + Q * 4;
        if (EPI == 0) {
            float b = bias[col];
            if (col < 512) {
#pragma unroll
                for (int r = 0; r < 4; ++r)
                    out_bf[(size_t)(row0 + r) * 512 + col] = f2bf(acc[nt][r] + b);
            } else {
                ushort4 pk;
                pk.x = f2bf(acc[nt][0] + b);
                pk.y = f2bf(acc[nt][1] + b);
                pk.z = f2bf(acc[nt][2] + b);
                pk.w = f2bf(acc[nt][3] + b);
                *(ushort4*)(out_vt + (size_t)(col - 512) * 8192 + row0) = pk;
            }
        } else {
#pragma unroll
            for (int r = 0; r < 4; ++r) {
                int row = row0 + r;
                float val = acc[nt][r];
                size_t oidx = (size_t)row * N + col;
                if (EPI == 1) {
                    val += bias[col] + resid[oidx];
                    out_f32[oidx] = val;
                    out_bf[oidx] = f2bf(fmaf(val, b2sc[col], b2sh[col]));
                } else if (EPI == 2) {
                    float gl = 0.5f * val * (1.f + erff(val * 0.70710678118654752f));
                    out_bf[oidx] = f2bf(gl);
                } else {
                    out_f32[oidx] = val + resid[oidx];
                }
            }
        }
    }
}

// ---------------------------------------------------------------------------
// Flash attention v8: sp=4 (512 s per WG, 8 kt iters) -> opart traffic halved;
// double-buffered 32 KB K/V LDS with prefetch under compute; 1D grid
// blk = qt*64 + sp*16 + bh (qt slowest, 64 % 8 == 0 preserves XCD L2 reuse).
// l via ones-row MFMA. 256 thr; bf16 partials.
// ---------------------------------------------------------------------------
static __device__ __forceinline__ void stage_tiles(const u16* kglob, const u16* vglob,
                                                   u16* kdst, u16* vdst,
                                                   int w, int lane, int kt) {
#pragma unroll
    for (int j = 0; j < 2; ++j) {
        int cw = (w * 2 + j) * 64 + lane;     // chunk 0..511
        int r = cw >> 3;                       // tile row 0..63
        int c = (cw & 7) ^ (r & 7);            // swizzled source chunk
        async_cp16(kglob + ((size_t)(kt * 64 + r)) * 512 + c * 8, kdst + (w * 2 + j) * 512);
        async_cp16(vglob + ((size_t)r) * 8192 + kt * 64 + c * 8, vdst + (w * 2 + j) * 512);
    }
}

__global__ __launch_bounds__(256) void attn_kernel(const u16* __restrict__ qk,
                                                   const u16* __restrict__ vT,
                                                   u16* __restrict__ opart,
                                                   float* __restrict__ lpart) {
    __shared__ u16 kbuf[2][4096];
    __shared__ u16 vbuf[2][4096];
    const int t = threadIdx.x;
    const int w = t >> 6, lane = t & 63;
    const int l = lane & 15, Q = lane >> 4;
    const int blk = blockIdx.x;
    const int qt = blk >> 6;          // 0..15  (slowest: XCD-local K/V reuse)
    const int sp = (blk >> 4) & 3;    // 0..3   (512 s each)
    const int bh = blk & 15;          // 0..15
    const int bb = bh >> 2, hd = bh & 3;
    const size_t rowbase = (size_t)bb * 2048;
    const int q0 = qt * 128 + w * 32;

    short8 qf[2][2];
#pragma unroll
    for (int qg = 0; qg < 2; ++qg)
#pragma unroll
        for (int kd = 0; kd < 2; ++kd)
            qf[qg][kd] = *(const short8*)(qk + (rowbase + q0 + qg * 16 + l) * 512
                                          + hd * 64 + kd * 32 + Q * 8);

    f32x4 o[2][4];
#pragma unroll
    for (int qg = 0; qg < 2; ++qg)
#pragma unroll
        for (int dt = 0; dt < 4; ++dt) o[qg][dt] = (f32x4){0.f, 0.f, 0.f, 0.f};
    f32x4 oL[2];                      // l accumulator via ones-MFMA
    oL[0] = (f32x4){0.f, 0.f, 0.f, 0.f};
    oL[1] = (f32x4){0.f, 0.f, 0.f, 0.f};
    union { u32 u[2]; short4v s4; } ones;
    ones.u[0] = 0x3F803F80u; ones.u[1] = 0x3F803F80u;   // bf16 1.0 x4

    const u16* kglob = qk + (rowbase + sp * 512) * 512 + 256 + hd * 64;
    const u16* vglob = vT + ((size_t)(hd * 64)) * 8192 + rowbase + sp * 512;

    stage_tiles(kglob, vglob, kbuf[0], vbuf[0], w, lane, 0);

    for (int kt = 0; kt < 8; ++kt) {
        __syncthreads();              // drains vmcnt: tile kt ready
        if (kt < 7)
            stage_tiles(kglob, vglob, kbuf[(kt + 1) & 1], vbuf[(kt + 1) & 1], w, lane, kt + 1);
        const u16* kb = kbuf[kt & 1];
        const u16* vb = vbuf[kt & 1];

        union { u32 u[2]; short4v s4; } pf[2][4];
#pragma unroll
        for (int st = 0; st < 4; ++st) {
            int r = st * 16 + l;
            short8 kf0 = *(const short8*)(kb + r * 64 + ((Q) ^ (r & 7)) * 8);
            short8 kf1 = *(const short8*)(kb + r * 64 + ((4 + Q) ^ (r & 7)) * 8);
#pragma unroll
            for (int qg = 0; qg < 2; ++qg) {
                f32x4 s = (f32x4){0.f, 0.f, 0.f, 0.f};
                s = __builtin_amdgcn_mfma_f32_16x16x32_bf16(kf0, qf[qg][0], s, 0, 0, 0);
                s = __builtin_amdgcn_mfma_f32_16x16x32_bf16(kf1, qf[qg][1], s, 0, 0, 0);
                float p0 = EXP2F(s[0]);
                float p1 = EXP2F(s[1]);
                float p2 = EXP2F(s[2]);
                float p3 = EXP2F(s[3]);
                pf[qg][st].u[0] = pack_bf2_trunc(p0, p1);
                pf[qg][st].u[1] = pack_bf2_trunc(p2, p3);
            }
        }

#pragma unroll
        for (int c = 0; c < 4; ++c) {
#pragma unroll
            for (int dt = 0; dt < 4; ++dt) {
                int r = dt * 16 + l;
                int slot = (2 * c + (Q >> 1)) ^ (r & 7);
                short4v vf = *(const short4v*)(vb + r * 64 + slot * 8 + (Q & 1) * 4);
                o[0][dt] = MFMA16(vf, pf[0][c].s4, o[0][dt]);
                o[1][dt] = MFMA16(vf, pf[1][c].s4, o[1][dt]);
            }
            oL[0] = MFMA16(ones.s4, pf[0][c].s4, oL[0]);
            oL[1] = MFMA16(ones.s4, pf[1][c].s4, oL[1]);
        }
    }

    // epilogue: bf16 partials; l = oL[qg][0] (each col q holds its sum)
    u16* ob = opart + (((size_t)sp * 16 + bh) * 2048 + q0) * 64;
#pragma unroll
    for (int qg = 0; qg < 2; ++qg)
#pragma unroll
        for (int dt = 0; dt < 4; ++dt) {
            ushort4 pk;
            pk.x = f2bf(o[qg][dt][0]);
            pk.y = f2bf(o[qg][dt][1]);
            pk.z = f2bf(o[qg][dt][2]);
            pk.w = f2bf(o[qg][dt][3]);
            *(ushort4*)(ob + (size_t)(qg * 16 + l) * 64 + dt * 16 + Q * 4) = pk;
        }
    if (Q == 0) {
        size_t lb = ((size_t)sp * 16 + bh) * 2048 + q0;
        lpart[lb + l] = oL[0][0];
        lpart[lb + 16 + l] = oL[1][0];
    }
}

// ---------------------------------------------------------------------------
// combine: ctx[b*2048+s][h*64+d] = sum_sp(o_sp) / sum_sp(l_sp) -> bf16
// ---------------------------------------------------------------------------
__global__ void combine_kernel(const u16* __restrict__ opart,
                               const float* __restrict__ lpart,
                               u16* __restrict__ ctx) {
    int idx = blockIdx.x * 256 + threadIdx.x;
    int e = idx * 4;
    int row = e >> 8, col = e & 255;
    int b = row >> 11, s = row & 2047, h = col >> 6, d = col & 63;
    float a0 = 0.f, a1 = 0.f, a2 = 0.f, a3 = 0.f, lsum = 0.f;
#pragma unroll
    for (int sp = 0; sp < 4; ++sp) {
        size_t pb = (((size_t)sp * 16 + b * 4 + h) * 2048 + s) * 64 + d;
        ushort4 ov = *(const ushort4*)(opart + pb);
        a0 += bf2f(ov.x); a1 += bf2f(ov.y); a2 += bf2f(ov.z); a3 += bf2f(ov.w);
        lsum += lpart[((size_t)sp * 16 + b * 4 + h) * 2048 + s];
    }
    float li = 1.0f / lsum;
    ushort4 pk;
    pk.x = f2bf(a0 * li);
    pk.y = f2bf(a1 * li);
    pk.z = f2bf(a2 * li);
    pk.w = f2bf(a3 * li);
    *(ushort4*)(ctx + e) = pk;
}

// ---------------------------------------------------------------------------
extern "C" void kernel_launch(void* const* d_in, const int* in_sizes, int n_in,
                              void* d_out, int out_size, void* d_ws, size_t ws_size,
                              hipStream_t stream) {
    (void)in_sizes; (void)n_in; (void)out_size; (void)ws_size;
    const float* x  = (const float*)d_in[0];
    const float* g1 = (const float*)d_in[1];
    const float* b1 = (const float*)d_in[2];
    const float* m1 = (const float*)d_in[3];
    const float* v1 = (const float*)d_in[4];
    const float* wq = (const float*)d_in[5];
    const float* bq = (const float*)d_in[6];
    const float* wk = (const float*)d_in[7];
    const float* bk = (const float*)d_in[8];
    const float* wv = (const float*)d_in[9];
    const float* bv = (const float*)d_in[10];
    const float* wo = (const float*)d_in[11];
    const float* bo = (const float*)d_in[12];
    const float* g2 = (const float*)d_in[13];
    const float* b2 = (const float*)d_in[14];
    const float* m2 = (const float*)d_in[15];
    const float* v2 = (const float*)d_in[16];
    const float* w1 = (const float*)d_in[17];
    const float* w2 = (const float*)d_in[18];

    char* ws = (char*)d_ws;
    u16*   qkb    = (u16*)(ws + (0ull << 20));    // [8192][512] bf16, 8 MB
    u16*   vTb    = (u16*)(ws + (8ull << 20));    // [256][8192] bf16, 4 MB
    u16*   h_buf  = (u16*)(ws + (12ull << 20));   // [8192][256] bf16, 4 MB
    u16*   ctx    = (u16*)(ws + (16ull << 20));   // [8192][256] bf16, 4 MB
    float* x1     = (float*)(ws + (20ull << 20)); // [8192][256] f32, 8 MB
    u16*   h2     = (u16*)(ws + (28ull << 20));   // [8192][256] bf16, 4 MB
    u16*   gbuf   = (u16*)(ws + (32ull << 20));   // [8192][1024] bf16, 16 MB
    u16*   opart  = (u16*)(ws + (48ull << 20));   // [4][16][2048][64] bf16, 16 MB
    float* lpart  = (float*)(ws + (80ull << 20)); // [4][16][2048] f32, 512 KB
    u16*   wqkvT  = (u16*)(ws + (81ull << 20));   // [768][256] bf16
    u16*   woT    = (u16*)(ws + (82ull << 20));   // [256][256]
    u16*   w1T    = (u16*)(ws + (83ull << 20));   // [1024][256]
    u16*   w2T    = (u16*)(ws + (84ull << 20));   // [256][1024]
    float* bqkv   = (float*)(ws + (85ull << 20)); // [768]
    float* bn2sc  = (float*)(ws + (85ull << 20) + 4096);
    float* bn2sh  = (float*)(ws + (85ull << 20) + 8192);
    float* out    = (float*)d_out;

    prep_bn1_kernel<<<5125, 256, 0, stream>>>(x, wq, wk, wv, wo, w1, w2, bq, bk, bv,
                                              g1, b1, m1, v1, g2, b2, m2, v2,
                                              h_buf, wqkvT, woT, w1T, w2T, bqkv,
                                              bn2sc, bn2sh);
    // QKV projection (q|k row-major into qkb; v transposed into vTb)
    gemm64<0><<<dim3(128, 12), 256, 0, stream>>>(
        h_buf, wqkvT, 8192, 768, 256, bqkv, nullptr, nullptr, qkb, vTb, nullptr, nullptr);
    // attention partials (1D grid, qt slowest for XCD L2 reuse) + combine
    attn_kernel<<<1024, 256, 0, stream>>>(qkb, vTb, opart, lpart);
    combine_kernel<<<2048, 256, 0, stream>>>(opart, lpart, ctx);
    // O projection + residual + bn2
    gemm64<1><<<dim3(128, 4), 256, 0, stream>>>(
        ctx, woT, 8192, 256, 256, bo, x, x1, h2, nullptr, bn2sc, bn2sh);
    // FFN1 + gelu
    gemm64<2><<<dim3(128, 16), 256, 0, stream>>>(
        h2, w1T, 8192, 1024, 256, nullptr, nullptr, nullptr, gbuf, nullptr, nullptr, nullptr);
    // FFN2 + residual -> out
    gemm64<3><<<dim3(128, 4), 256, 0, stream>>>(
        gbuf, w2T, 8192, 256, 1024, nullptr, x1, out, nullptr, nullptr, nullptr, nullptr);
}

// Round 13
// 178.174 us; speedup vs baseline: 1.1357x; 1.0170x over previous
//
#include <hip/hip_runtime.h>

typedef unsigned short u16;
typedef unsigned int u32;
typedef short short8 __attribute__((ext_vector_type(8)));
typedef short short4v __attribute__((ext_vector_type(4)));
typedef float f32x4 __attribute__((ext_vector_type(4)));

#define EPS 1e-3f
#define C1F 0.18033688011112042f   // 0.125 * log2(e), folded into wk/bk in prep

#if defined(__HIP_DEVICE_COMPILE__)
#define MFMA16(a, b, c) __builtin_amdgcn_mfma_f32_16x16x16bf16_1k(a, b, c, 0, 0, 0)
#define EXP2F(x) __builtin_amdgcn_exp2f(x)
#else
#define MFMA16(a, b, c) (c)
#define EXP2F(x) exp2f(x)
#endif

static __device__ __forceinline__ u16 f2bf(float f) {
    u32 u = __float_as_uint(f);
    u += 0x7fffu + ((u >> 16) & 1u);   // round-to-nearest-even
    return (u16)(u >> 16);
}
static __device__ __forceinline__ float bf2f(u16 v) {
    u32 u = (u32)v << 16;
    return __uint_as_float(u);
}
// truncation pack (P in [0,1], trunc error <0.4% rel — fine for softmax weights)
static __device__ __forceinline__ u32 pack_bf2_trunc(float a, float b) {
    return __builtin_amdgcn_perm(__float_as_uint(b), __float_as_uint(a), 0x07060302u);
}
static __device__ __forceinline__ void async_cp16(const void* g, void* l) {
    __builtin_amdgcn_global_load_lds(
        (const __attribute__((address_space(1))) unsigned int*)g,
        (__attribute__((address_space(3))) unsigned int*)l, 16, 0, 0);
}

// ---------------------------------------------------------------------------
// prep + bn1 merged. Blocks [0,2048): bn1(x)->h bf16. Blocks [2048,5125):
// weight transposes (coalesced reads), bqkv, bn sc/sh.
// ---------------------------------------------------------------------------
__global__ void prep_bn1_kernel(const float* __restrict__ x,
                            const float* __restrict__ wq, const float* __restrict__ wk,
                            const float* __restrict__ wv, const float* __restrict__ wo,
                            const float* __restrict__ w1, const float* __restrict__ w2,
                            const float* __restrict__ bq, const float* __restrict__ bk,
                            const float* __restrict__ bv,
                            const float* __restrict__ g1, const float* __restrict__ b1,
                            const float* __restrict__ m1, const float* __restrict__ v1,
                            const float* __restrict__ g2, const float* __restrict__ b2,
                            const float* __restrict__ m2, const float* __restrict__ v2,
                            u16* __restrict__ h,
                            u16* __restrict__ wqkvT, u16* __restrict__ woT,
                            u16* __restrict__ w1T, u16* __restrict__ w2T,
                            float* __restrict__ bqkv,
                            float* __restrict__ bn2sc, float* __restrict__ bn2sh) {
    int bid = blockIdx.x;
    if (bid < 2048) {                         // bn1 part
        int idx = bid * 256 + threadIdx.x;
        int base = idx * 4;
        int c = base & 255;
        float4 xv = *(const float4*)(x + base);
        ushort4 pk;
        {
            float sc0 = g1[c] * rsqrtf(v1[c] + EPS);
            pk.x = f2bf(fmaf(xv.x, sc0, b1[c] - m1[c] * sc0));
            float sc1 = g1[c+1] * rsqrtf(v1[c+1] + EPS);
            pk.y = f2bf(fmaf(xv.y, sc1, b1[c+1] - m1[c+1] * sc1));
            float sc2 = g1[c+2] * rsqrtf(v1[c+2] + EPS);
            pk.z = f2bf(fmaf(xv.z, sc2, b1[c+2] - m1[c+2] * sc2));
            float sc3 = g1[c+3] * rsqrtf(v1[c+3] + EPS);
            pk.w = f2bf(fmaf(xv.w, sc3, b1[c+3] - m1[c+3] * sc3));
        }
        *(ushort4*)(h + base) = pk;
        return;
    }
    int idx = (bid - 2048) * 256 + threadIdx.x;
    if (idx < 196608) {                       // wqkvT [768][256]
        int sec = idx >> 16;                  // 0=q, 1=k, 2=v
        int i = idx & 65535;
        int k = i >> 8, n = i & 255;
        const float* w = sec == 0 ? wq : (sec == 1 ? wk : wv);
        float v = w[i];                       // coalesced: w[k*256+n]
        if (sec == 1) v *= C1F;
        wqkvT[(sec * 256 + n) * 256 + k] = f2bf(v);
    } else if (idx < 262144) {                // woT [256][256]
        int i = idx - 196608; int k = i >> 8, n = i & 255;
        woT[n * 256 + k] = f2bf(wo[i]);
    } else if (idx < 524288) {                // w1T [1024][256]
        int i = idx - 262144; int k = i >> 10, n = i & 1023;
        w1T[n * 256 + k] = f2bf(w1[i]);
    } else if (idx < 786432) {                // w2T [256][1024]
        int i = idx - 524288; int k = i >> 8, n = i & 255;
        w2T[n * 1024 + k] = f2bf(w2[i]);
    } else if (idx < 787200) {                // bqkv [768]
        int i = idx - 786432;
        bqkv[i] = (i < 256) ? bq[i] : (i < 512 ? bk[i - 256] * C1F : bv[i - 512]);
    } else if (idx < 787456) {                // bn2 sc/sh
        int i = idx - 787200;
        float sc = g2[i] * rsqrtf(v2[i] + EPS);
        bn2sc[i] = sc; bn2sh[i] = b2[i] - m2[i] * sc;
    }
}

// ---------------------------------------------------------------------------
// 64x128-tile double-buffered GEMM (QKV, FFN1). Wave = 32 rows x 64 cols
// (w&1 = row half, w>>1 = col half). 48 KB LDS.
// EPI 0: qkv (col<512: +bias->row-major qkb; col>=512: +bias->vT transposed)
// EPI 2: gelu->bf16
// ---------------------------------------------------------------------------
template <int EPI>
__global__ __launch_bounds__(256) void gemm128(
        const u16* __restrict__ A, const u16* __restrict__ Bt,
        int M, int N, int K,
        const float* __restrict__ bias, u16* __restrict__ out_bf,
        u16* __restrict__ out_vt) {
    __shared__ u16 abuf[2][4096];    // 64 x 64k
    __shared__ u16 bbuf[2][8192];    // 128 x 64k
    const int t = threadIdx.x;
    const int w = t >> 6, lane = t & 63;
    const int l = lane & 15, Q = lane >> 4;
    const int m0 = blockIdx.x * 64;
    const int n0 = blockIdx.y * 128;
    const int rh = (w & 1) * 32;
    const int ch = (w >> 1) * 64;

    f32x4 acc[2][4];
#pragma unroll
    for (int mt = 0; mt < 2; ++mt)
#pragma unroll
        for (int nt = 0; nt < 4; ++nt) acc[mt][nt] = (f32x4){0.f, 0.f, 0.f, 0.f};

    auto stage = [&](int k0, int b) {
#pragma unroll
        for (int j = 0; j < 2; ++j) {
            int idx = j * 256 + t;
            int r = idx >> 3, c8 = idx & 7;
            int sc = c8 ^ (r & 7);
            async_cp16(A + (size_t)(m0 + r) * K + k0 + sc * 8, abuf[b] + idx * 8);
        }
#pragma unroll
        for (int j = 0; j < 4; ++j) {
            int idx = j * 256 + t;
            int r = idx >> 3, c8 = idx & 7;
            int sc = c8 ^ (r & 7);
            async_cp16(Bt + (size_t)(n0 + r) * K + k0 + sc * 8, bbuf[b] + idx * 8);
        }
    };

    const int nit = K >> 6;
    stage(0, 0);
    for (int i = 0; i < nit; ++i) {
        __syncthreads();              // vmcnt drained: tile i ready
        if (i + 1 < nit) stage((i + 1) << 6, (i + 1) & 1);
        const u16* ab = abuf[i & 1];
        const u16* bb = bbuf[i & 1];
#pragma unroll
        for (int kd = 0; kd < 2; ++kd) {
            short8 afr[2], bfr[4];
#pragma unroll
            for (int mt = 0; mt < 2; ++mt) {
                int ar = rh + mt * 16 + l;
                afr[mt] = *(const short8*)(ab + ar * 64 + (((kd * 4 + Q) ^ (ar & 7))) * 8);
            }
#pragma unroll
            for (int nt = 0; nt < 4; ++nt) {
                int br = ch + nt * 16 + l;
                bfr[nt] = *(const short8*)(bb + br * 64 + (((kd * 4 + Q) ^ (br & 7))) * 8);
            }
#pragma unroll
            for (int mt = 0; mt < 2; ++mt)
#pragma unroll
                for (int nt = 0; nt < 4; ++nt)
                    acc[mt][nt] = __builtin_amdgcn_mfma_f32_16x16x32_bf16(afr[mt], bfr[nt], acc[mt][nt], 0, 0, 0);
        }
    }

#pragma unroll
    for (int mt = 0; mt < 2; ++mt)
#pragma unroll
        for (int nt = 0; nt < 4; ++nt) {
            int col = n0 + ch + nt * 16 + l;
            int row0 = m0 + rh + mt * 16 + Q * 4;
            if (EPI == 0) {
                float b = bias[col];
                if (col < 512) {
#pragma unroll
                    for (int r = 0; r < 4; ++r)
                        out_bf[(size_t)(row0 + r) * 512 + col] = f2bf(acc[mt][nt][r] + b);
                } else {
                    ushort4 pk;
                    pk.x = f2bf(acc[mt][nt][0] + b);
                    pk.y = f2bf(acc[mt][nt][1] + b);
                    pk.z = f2bf(acc[mt][nt][2] + b);
                    pk.w = f2bf(acc[mt][nt][3] + b);
                    *(ushort4*)(out_vt + (size_t)(col - 512) * 8192 + row0) = pk;
                }
            } else {
#pragma unroll
                for (int r = 0; r < 4; ++r) {
                    float val = acc[mt][nt][r];
                    float gl = 0.5f * val * (1.f + erff(val * 0.70710678118654752f));
                    out_bf[(size_t)(row0 + r) * N + col] = f2bf(gl);
                }
            }
        }
}

// ---------------------------------------------------------------------------
// 64x64-tile double-buffered GEMM (kept for FFN2). EPI 3: +resid->f32
// ---------------------------------------------------------------------------
__global__ __launch_bounds__(256) void gemm64_res(
        const u16* __restrict__ A, const u16* __restrict__ Bt,
        int M, int N, int K,
        const float* __restrict__ resid, float* __restrict__ out_f32) {
    __shared__ u16 abuf[2][4096];
    __shared__ u16 bbuf[2][4096];
    const int t = threadIdx.x;
    const int w = t >> 6, lane = t & 63;
    const int l = lane & 15, Q = lane >> 4;
    const int m0 = blockIdx.x * 64;
    const int n0 = blockIdx.y * 64;

    f32x4 acc[4];
#pragma unroll
    for (int nt = 0; nt < 4; ++nt) acc[nt] = (f32x4){0.f, 0.f, 0.f, 0.f};

    auto stage = [&](int k0, int b) {
#pragma unroll
        for (int j = 0; j < 2; ++j) {
            int idx = j * 256 + t;
            int r = idx >> 3, c8 = idx & 7;
            int sc = c8 ^ (r & 7);
            async_cp16(A + (size_t)(m0 + r) * K + k0 + sc * 8, abuf[b] + idx * 8);
        }
#pragma unroll
        for (int j = 0; j < 2; ++j) {
            int idx = j * 256 + t;
            int r = idx >> 3, c8 = idx & 7;
            int sc = c8 ^ (r & 7);
            async_cp16(Bt + (size_t)(n0 + r) * K + k0 + sc * 8, bbuf[b] + idx * 8);
        }
    };

    const int nit = K >> 6;
    stage(0, 0);
    for (int i = 0; i < nit; ++i) {
        __syncthreads();
        if (i + 1 < nit) stage((i + 1) << 6, (i + 1) & 1);
        const u16* ab = abuf[i & 1];
        const u16* bb = bbuf[i & 1];
#pragma unroll
        for (int kd = 0; kd < 2; ++kd) {
            int ar = w * 16 + l;
            short8 afr = *(const short8*)(ab + ar * 64 + (((kd * 4 + Q) ^ (ar & 7))) * 8);
#pragma unroll
            for (int nt = 0; nt < 4; ++nt) {
                int r = nt * 16 + l;
                short8 bfr = *(const short8*)(bb + r * 64 + (((kd * 4 + Q) ^ (r & 7))) * 8);
                acc[nt] = __builtin_amdgcn_mfma_f32_16x16x32_bf16(afr, bfr, acc[nt], 0, 0, 0);
            }
        }
    }

#pragma unroll
    for (int nt = 0; nt < 4; ++nt) {
        int col = n0 + nt * 16 + l;
        int row0 = m0 + w * 16 + Q * 4;
#pragma unroll
        for (int r = 0; r < 4; ++r) {
            size_t oidx = (size_t)(row0 + r) * N + col;
            out_f32[oidx] = acc[nt][r] + resid[oidx];
        }
    }
}

// ---------------------------------------------------------------------------
// O-proj with FUSED combine: A-tile for k-chunk hd is ctx[rows][head hd] =
// (sum_sp opart)/(sum_sp lpart), computed in f32 during A-staging (VGPR loads
// -> combine -> ds_write_b128, same XOR swizzle). B (woT) async-LDS dbuf.
// Epilogue: +bias+resid -> f32 x1 AND bn2 -> bf16 h2. Grid (128, 4).
// ---------------------------------------------------------------------------
__global__ __launch_bounds__(256) void gemm_oproj(
        const u16* __restrict__ opart, const float* __restrict__ lpart,
        const u16* __restrict__ Bt,
        const float* __restrict__ bias, const float* __restrict__ resid,
        float* __restrict__ out_f32, u16* __restrict__ out_bf,
        const float* __restrict__ b2sc, const float* __restrict__ b2sh) {
    __shared__ u16 abuf[4096];        // single-buffered combined-A (8 KB)
    __shared__ u16 bbuf[2][4096];
    const int t = threadIdx.x;
    const int w = t >> 6, lane = t & 63;
    const int l = lane & 15, Q = lane >> 4;
    const int m0 = blockIdx.x * 64;
    const int n0 = blockIdx.y * 64;
    const size_t SPSTR = (size_t)16 * 2048 * 64;   // opart sp stride (elems)

    f32x4 acc[4];
#pragma unroll
    for (int nt = 0; nt < 4; ++nt) acc[nt] = (f32x4){0.f, 0.f, 0.f, 0.f};

    auto stageB = [&](int k0, int b) {
#pragma unroll
        for (int j = 0; j < 2; ++j) {
            int idx = j * 256 + t;
            int r = idx >> 3, c8 = idx & 7;
            int sc = c8 ^ (r & 7);
            async_cp16(Bt + (size_t)(n0 + r) * 256 + k0 + sc * 8, bbuf[b] + idx * 8);
        }
    };

    stageB(0, 0);
    for (int i = 0; i < 4; ++i) {     // k0 = i*64, head hd = i
        // ---- fused combine for A-tile chunk (VGPR path)
        uint4 aw[2];
#pragma unroll
        for (int j = 0; j < 2; ++j) {
            int idx = j * 256 + t;
            int r = idx >> 3, c8 = idx & 7;
            int dc = c8 ^ (r & 7);            // global d-chunk stored in this slot
            int row = m0 + r;
            int bh = (row >> 11) * 4 + i;
            int q = row & 2047;
            size_t lb = (size_t)bh * 2048 + q;
            float ls = lpart[lb] + lpart[lb + 32768] + lpart[lb + 65536] + lpart[lb + 98304];
            float inv = 1.0f / ls;
            size_t base = ((size_t)bh * 2048 + q) * 64 + dc * 8;
            uint4 v0 = *(const uint4*)(opart + base);
            uint4 v1 = *(const uint4*)(opart + SPSTR + base);
            uint4 v2 = *(const uint4*)(opart + 2 * SPSTR + base);
            uint4 v3 = *(const uint4*)(opart + 3 * SPSTR + base);
            u32 o[4];
            const u32* p0 = &v0.x; const u32* p1 = &v1.x;
            const u32* p2 = &v2.x; const u32* p3 = &v3.x;
#pragma unroll
            for (int e = 0; e < 4; ++e) {
                float lo = __uint_as_float(p0[e] << 16) + __uint_as_float(p1[e] << 16)
                         + __uint_as_float(p2[e] << 16) + __uint_as_float(p3[e] << 16);
                float hi = __uint_as_float(p0[e] & 0xffff0000u) + __uint_as_float(p1[e] & 0xffff0000u)
                         + __uint_as_float(p2[e] & 0xffff0000u) + __uint_as_float(p3[e] & 0xffff0000u);
                o[e] = (u32)f2bf(lo * inv) | ((u32)f2bf(hi * inv) << 16);
            }
            aw[j] = make_uint4(o[0], o[1], o[2], o[3]);
        }
        __syncthreads();              // prev compute done reading abuf; B[i] drained
#pragma unroll
        for (int j = 0; j < 2; ++j)
            *(uint4*)(abuf + ((size_t)(j * 256 + t)) * 8) = aw[j];
        if (i < 3) stageB((i + 1) * 64, (i + 1) & 1);
        __syncthreads();              // abuf visible to all waves
        const u16* bb = bbuf[i & 1];
#pragma unroll
        for (int kd = 0; kd < 2; ++kd) {
            int ar = w * 16 + l;
            short8 afr = *(const short8*)(abuf + ar * 64 + (((kd * 4 + Q) ^ (ar & 7))) * 8);
#pragma unroll
            for (int nt = 0; nt < 4; ++nt) {
                int r = nt * 16 + l;
                short8 bfr = *(const short8*)(bb + r * 64 + (((kd * 4 + Q) ^ (r & 7))) * 8);
                acc[nt] = __builtin_amdgcn_mfma_f32_16x16x32_bf16(afr, bfr, acc[nt], 0, 0, 0);
            }
        }
    }

#pragma unroll
    for (int nt = 0; nt < 4; ++nt) {
        int col = n0 + nt * 16 + l;
        int row0 = m0 + w * 16 + Q * 4;
#pragma unroll
        for (int r = 0; r < 4; ++r) {
            size_t oidx = (size_t)(row0 + r) * 256 + col;
            float val = acc[nt][r] + bias[col] + resid[oidx];
            out_f32[oidx] = val;
            out_bf[oidx] = f2bf(fmaf(val, b2sc[col], b2sh[col]));
        }
    }
}

// ---------------------------------------------------------------------------
// Flash attention v8 (unchanged from R12): sp=4, double-buffered 32 KB LDS,
// 1D grid blk = qt*64 + sp*16 + bh (qt slowest, XCD L2 reuse), l via
// ones-row MFMA. 256 thr; bf16 partials.
// ---------------------------------------------------------------------------
static __device__ __forceinline__ void stage_tiles(const u16* kglob, const u16* vglob,
                                                   u16* kdst, u16* vdst,
                                                   int w, int lane, int kt) {
#pragma unroll
    for (int j = 0; j < 2; ++j) {
        int cw = (w * 2 + j) * 64 + lane;     // chunk 0..511
        int r = cw >> 3;                       // tile row 0..63
        int c = (cw & 7) ^ (r & 7);            // swizzled source chunk
        async_cp16(kglob + ((size_t)(kt * 64 + r)) * 512 + c * 8, kdst + (w * 2 + j) * 512);
        async_cp16(vglob + ((size_t)r) * 8192 + kt * 64 + c * 8, vdst + (w * 2 + j) * 512);
    }
}

__global__ __launch_bounds__(256) void attn_kernel(const u16* __restrict__ qk,
                                                   const u16* __restrict__ vT,
                                                   u16* __restrict__ opart,
                                                   float* __restrict__ lpart) {
    __shared__ u16 kbuf[2][4096];
    __shared__ u16 vbuf[2][4096];
    const int t = threadIdx.x;
    const int w = t >> 6, lane = t & 63;
    const int l = lane & 15, Q = lane >> 4;
    const int blk = blockIdx.x;
    const int qt = blk >> 6;          // 0..15  (slowest: XCD-local K/V reuse)
    const int sp = (blk >> 4) & 3;    // 0..3   (512 s each)
    const int bh = blk & 15;          // 0..15
    const int bb = bh >> 2, hd = bh & 3;
    const size_t rowbase = (size_t)bb * 2048;
    const int q0 = qt * 128 + w * 32;

    short8 qf[2][2];
#pragma unroll
    for (int qg = 0; qg < 2; ++qg)
#pragma unroll
        for (int kd = 0; kd < 2; ++kd)
            qf[qg][kd] = *(const short8*)(qk + (rowbase + q0 + qg * 16 + l) * 512
                                          + hd * 64 + kd * 32 + Q * 8);

    f32x4 o[2][4];
#pragma unroll
    for (int qg = 0; qg < 2; ++qg)
#pragma unroll
        for (int dt = 0; dt < 4; ++dt) o[qg][dt] = (f32x4){0.f, 0.f, 0.f, 0.f};
    f32x4 oL[2];                      // l accumulator via ones-MFMA
    oL[0] = (f32x4){0.f, 0.f, 0.f, 0.f};
    oL[1] = (f32x4){0.f, 0.f, 0.f, 0.f};
    union { u32 u[2]; short4v s4; } ones;
    ones.u[0] = 0x3F803F80u; ones.u[1] = 0x3F803F80u;   // bf16 1.0 x4

    const u16* kglob = qk + (rowbase + sp * 512) * 512 + 256 + hd * 64;
    const u16* vglob = vT + ((size_t)(hd * 64)) * 8192 + rowbase + sp * 512;

    stage_tiles(kglob, vglob, kbuf[0], vbuf[0], w, lane, 0);

    for (int kt = 0; kt < 8; ++kt) {
        __syncthreads();              // drains vmcnt: tile kt ready
        if (kt < 7)
            stage_tiles(kglob, vglob, kbuf[(kt + 1) & 1], vbuf[(kt + 1) & 1], w, lane, kt + 1);
        const u16* kb = kbuf[kt & 1];
        const u16* vb = vbuf[kt & 1];

        union { u32 u[2]; short4v s4; } pf[2][4];
#pragma unroll
        for (int st = 0; st < 4; ++st) {
            int r = st * 16 + l;
            short8 kf0 = *(const short8*)(kb + r * 64 + ((Q) ^ (r & 7)) * 8);
            short8 kf1 = *(const short8*)(kb + r * 64 + ((4 + Q) ^ (r & 7)) * 8);
#pragma unroll
            for (int qg = 0; qg < 2; ++qg) {
                f32x4 s = (f32x4){0.f, 0.f, 0.f, 0.f};
                s = __builtin_amdgcn_mfma_f32_16x16x32_bf16(kf0, qf[qg][0], s, 0, 0, 0);
                s = __builtin_amdgcn_mfma_f32_16x16x32_bf16(kf1, qf[qg][1], s, 0, 0, 0);
                float p0 = EXP2F(s[0]);
                float p1 = EXP2F(s[1]);
                float p2 = EXP2F(s[2]);
                float p3 = EXP2F(s[3]);
                pf[qg][st].u[0] = pack_bf2_trunc(p0, p1);
                pf[qg][st].u[1] = pack_bf2_trunc(p2, p3);
            }
        }

#pragma unroll
        for (int c = 0; c < 4; ++c) {
#pragma unroll
            for (int dt = 0; dt < 4; ++dt) {
                int r = dt * 16 + l;
                int slot = (2 * c + (Q >> 1)) ^ (r & 7);
                short4v vf = *(const short4v*)(vb + r * 64 + slot * 8 + (Q & 1) * 4);
                o[0][dt] = MFMA16(vf, pf[0][c].s4, o[0][dt]);
                o[1][dt] = MFMA16(vf, pf[1][c].s4, o[1][dt]);
            }
            oL[0] = MFMA16(ones.s4, pf[0][c].s4, oL[0]);
            oL[1] = MFMA16(ones.s4, pf[1][c].s4, oL[1]);
        }
    }

    // epilogue: bf16 partials; l = oL[qg][0] (each col q holds its sum)
    u16* ob = opart + (((size_t)sp * 16 + bh) * 2048 + q0) * 64;
#pragma unroll
    for (int qg = 0; qg < 2; ++qg)
#pragma unroll
        for (int dt = 0; dt < 4; ++dt) {
            ushort4 pk;
            pk.x = f2bf(o[qg][dt][0]);
            pk.y = f2bf(o[qg][dt][1]);
            pk.z = f2bf(o[qg][dt][2]);
            pk.w = f2bf(o[qg][dt][3]);
            *(ushort4*)(ob + (size_t)(qg * 16 + l) * 64 + dt * 16 + Q * 4) = pk;
        }
    if (Q == 0) {
        size_t lb = ((size_t)sp * 16 + bh) * 2048 + q0;
        lpart[lb + l] = oL[0][0];
        lpart[lb + 16 + l] = oL[1][0];
    }
}

// ---------------------------------------------------------------------------
extern "C" void kernel_launch(void* const* d_in, const int* in_sizes, int n_in,
                              void* d_out, int out_size, void* d_ws, size_t ws_size,
                              hipStream_t stream) {
    (void)in_sizes; (void)n_in; (void)out_size; (void)ws_size;
    const float* x  = (const float*)d_in[0];
    const float* g1 = (const float*)d_in[1];
    const float* b1 = (const float*)d_in[2];
    const float* m1 = (const float*)d_in[3];
    const float* v1 = (const float*)d_in[4];
    const float* wq = (const float*)d_in[5];
    const float* bq = (const float*)d_in[6];
    const float* wk = (const float*)d_in[7];
    const float* bk = (const float*)d_in[8];
    const float* wv = (const float*)d_in[9];
    const float* bv = (const float*)d_in[10];
    const float* wo = (const float*)d_in[11];
    const float* bo = (const float*)d_in[12];
    const float* g2 = (const float*)d_in[13];
    const float* b2 = (const float*)d_in[14];
    const float* m2 = (const float*)d_in[15];
    const float* v2 = (const float*)d_in[16];
    const float* w1 = (const float*)d_in[17];
    const float* w2 = (const float*)d_in[18];

    char* ws = (char*)d_ws;
    u16*   qkb    = (u16*)(ws + (0ull << 20));    // [8192][512] bf16, 8 MB
    u16*   vTb    = (u16*)(ws + (8ull << 20));    // [256][8192] bf16, 4 MB
    u16*   h_buf  = (u16*)(ws + (12ull << 20));   // [8192][256] bf16, 4 MB
    float* x1     = (float*)(ws + (20ull << 20)); // [8192][256] f32, 8 MB
    u16*   h2     = (u16*)(ws + (28ull << 20));   // [8192][256] bf16, 4 MB
    u16*   gbuf   = (u16*)(ws + (32ull << 20));   // [8192][1024] bf16, 16 MB
    u16*   opart  = (u16*)(ws + (48ull << 20));   // [4][16][2048][64] bf16, 16 MB
    float* lpart  = (float*)(ws + (80ull << 20)); // [4][16][2048] f32, 512 KB
    u16*   wqkvT  = (u16*)(ws + (81ull << 20));   // [768][256] bf16
    u16*   woT    = (u16*)(ws + (82ull << 20));   // [256][256]
    u16*   w1T    = (u16*)(ws + (83ull << 20));   // [1024][256]
    u16*   w2T    = (u16*)(ws + (84ull << 20));   // [256][1024]
    float* bqkv   = (float*)(ws + (85ull << 20)); // [768]
    float* bn2sc  = (float*)(ws + (85ull << 20) + 4096);
    float* bn2sh  = (float*)(ws + (85ull << 20) + 8192);
    float* out    = (float*)d_out;

    prep_bn1_kernel<<<5125, 256, 0, stream>>>(x, wq, wk, wv, wo, w1, w2, bq, bk, bv,
                                              g1, b1, m1, v1, g2, b2, m2, v2,
                                              h_buf, wqkvT, woT, w1T, w2T, bqkv,
                                              bn2sc, bn2sh);
    // QKV projection, 64x128 tiles (q|k row-major into qkb; v transposed into vTb)
    gemm128<0><<<dim3(128, 6), 256, 0, stream>>>(
        h_buf, wqkvT, 8192, 768, 256, bqkv, qkb, vTb);
    // attention partials (1D grid, qt slowest for XCD L2 reuse)
    attn_kernel<<<1024, 256, 0, stream>>>(qkb, vTb, opart, lpart);
    // O projection with fused combine + residual + bn2
    gemm_oproj<<<dim3(128, 4), 256, 0, stream>>>(
        opart, lpart, woT, bo, x, x1, h2, bn2sc, bn2sh);
    // FFN1 + gelu, 64x128 tiles
    gemm128<2><<<dim3(128, 8), 256, 0, stream>>>(
        h2, w1T, 8192, 1024, 256, nullptr, gbuf, nullptr);
    // FFN2 + residual -> out
    gemm64_res<<<dim3(128, 4), 256, 0, stream>>>(
        gbuf, w2T, 8192, 256, 1024, x1, out);
}

// Round 14
// 176.688 us; speedup vs baseline: 1.1452x; 1.0084x over previous
//
#include <hip/hip_runtime.h>

typedef unsigned short u16;
typedef unsigned int u32;
typedef short short8 __attribute__((ext_vector_type(8)));
typedef short short4v __attribute__((ext_vector_type(4)));
typedef float f32x4 __attribute__((ext_vector_type(4)));

#define EPS 1e-3f
#define C1F 0.18033688011112042f   // 0.125 * log2(e), folded into wk/bk in prep

#if defined(__HIP_DEVICE_COMPILE__)
#define MFMA16(a, b, c) __builtin_amdgcn_mfma_f32_16x16x16bf16_1k(a, b, c, 0, 0, 0)
#define EXP2F(x) __builtin_amdgcn_exp2f(x)
#else
#define MFMA16(a, b, c) (c)
#define EXP2F(x) exp2f(x)
#endif

static __device__ __forceinline__ u16 f2bf(float f) {
    u32 u = __float_as_uint(f);
    u += 0x7fffu + ((u >> 16) & 1u);   // round-to-nearest-even
    return (u16)(u >> 16);
}
static __device__ __forceinline__ float bf2f(u16 v) {
    u32 u = (u32)v << 16;
    return __uint_as_float(u);
}
// truncation pack (P in [0,1], trunc error <0.4% rel — fine for softmax weights)
static __device__ __forceinline__ u32 pack_bf2_trunc(float a, float b) {
    return __builtin_amdgcn_perm(__float_as_uint(b), __float_as_uint(a), 0x07060302u);
}
static __device__ __forceinline__ void async_cp16(const void* g, void* l) {
    __builtin_amdgcn_global_load_lds(
        (const __attribute__((address_space(1))) unsigned int*)g,
        (__attribute__((address_space(3))) unsigned int*)l, 16, 0, 0);
}

// ---------------------------------------------------------------------------
// prep + bn1 merged. Blocks [0,2048): bn1(x)->h bf16. Blocks [2048,5125):
// weight transposes (coalesced reads), bqkv, bn sc/sh.
// ---------------------------------------------------------------------------
__global__ void prep_bn1_kernel(const float* __restrict__ x,
                            const float* __restrict__ wq, const float* __restrict__ wk,
                            const float* __restrict__ wv, const float* __restrict__ wo,
                            const float* __restrict__ w1, const float* __restrict__ w2,
                            const float* __restrict__ bq, const float* __restrict__ bk,
                            const float* __restrict__ bv,
                            const float* __restrict__ g1, const float* __restrict__ b1,
                            const float* __restrict__ m1, const float* __restrict__ v1,
                            const float* __restrict__ g2, const float* __restrict__ b2,
                            const float* __restrict__ m2, const float* __restrict__ v2,
                            u16* __restrict__ h,
                            u16* __restrict__ wqkvT, u16* __restrict__ woT,
                            u16* __restrict__ w1T, u16* __restrict__ w2T,
                            float* __restrict__ bqkv,
                            float* __restrict__ bn2sc, float* __restrict__ bn2sh) {
    int bid = blockIdx.x;
    if (bid < 2048) {                         // bn1 part
        int idx = bid * 256 + threadIdx.x;
        int base = idx * 4;
        int c = base & 255;
        float4 xv = *(const float4*)(x + base);
        ushort4 pk;
        {
            float sc0 = g1[c] * rsqrtf(v1[c] + EPS);
            pk.x = f2bf(fmaf(xv.x, sc0, b1[c] - m1[c] * sc0));
            float sc1 = g1[c+1] * rsqrtf(v1[c+1] + EPS);
            pk.y = f2bf(fmaf(xv.y, sc1, b1[c+1] - m1[c+1] * sc1));
            float sc2 = g1[c+2] * rsqrtf(v1[c+2] + EPS);
            pk.z = f2bf(fmaf(xv.z, sc2, b1[c+2] - m1[c+2] * sc2));
            float sc3 = g1[c+3] * rsqrtf(v1[c+3] + EPS);
            pk.w = f2bf(fmaf(xv.w, sc3, b1[c+3] - m1[c+3] * sc3));
        }
        *(ushort4*)(h + base) = pk;
        return;
    }
    int idx = (bid - 2048) * 256 + threadIdx.x;
    if (idx < 196608) {                       // wqkvT [768][256]
        int sec = idx >> 16;                  // 0=q, 1=k, 2=v
        int i = idx & 65535;
        int k = i >> 8, n = i & 255;
        const float* w = sec == 0 ? wq : (sec == 1 ? wk : wv);
        float v = w[i];                       // coalesced: w[k*256+n]
        if (sec == 1) v *= C1F;
        wqkvT[(sec * 256 + n) * 256 + k] = f2bf(v);
    } else if (idx < 262144) {                // woT [256][256]
        int i = idx - 196608; int k = i >> 8, n = i & 255;
        woT[n * 256 + k] = f2bf(wo[i]);
    } else if (idx < 524288) {                // w1T [1024][256]
        int i = idx - 262144; int k = i >> 10, n = i & 1023;
        w1T[n * 256 + k] = f2bf(w1[i]);
    } else if (idx < 786432) {                // w2T [256][1024]
        int i = idx - 524288; int k = i >> 8, n = i & 255;
        w2T[n * 1024 + k] = f2bf(w2[i]);
    } else if (idx < 787200) {                // bqkv [768]
        int i = idx - 786432;
        bqkv[i] = (i < 256) ? bq[i] : (i < 512 ? bk[i - 256] * C1F : bv[i - 512]);
    } else if (idx < 787456) {                // bn2 sc/sh
        int i = idx - 787200;
        float sc = g2[i] * rsqrtf(v2[i] + EPS);
        bn2sc[i] = sc; bn2sh[i] = b2[i] - m2[i] * sc;
    }
}

// ---------------------------------------------------------------------------
// 64x128-tile double-buffered GEMM (QKV, FFN1). Wave = 32 rows x 64 cols
// (w&1 = row half, w>>1 = col half). 48 KB LDS.
// EPI 0: qkv (col<512: +bias->row-major qkb; col>=512: +bias->vT transposed)
// EPI 2: gelu->bf16
// ---------------------------------------------------------------------------
template <int EPI>
__global__ __launch_bounds__(256) void gemm128(
        const u16* __restrict__ A, const u16* __restrict__ Bt,
        int M, int N, int K,
        const float* __restrict__ bias, u16* __restrict__ out_bf,
        u16* __restrict__ out_vt) {
    __shared__ u16 abuf[2][4096];    // 64 x 64k
    __shared__ u16 bbuf[2][8192];    // 128 x 64k
    const int t = threadIdx.x;
    const int w = t >> 6, lane = t & 63;
    const int l = lane & 15, Q = lane >> 4;
    const int m0 = blockIdx.x * 64;
    const int n0 = blockIdx.y * 128;
    const int rh = (w & 1) * 32;
    const int ch = (w >> 1) * 64;

    f32x4 acc[2][4];
#pragma unroll
    for (int mt = 0; mt < 2; ++mt)
#pragma unroll
        for (int nt = 0; nt < 4; ++nt) acc[mt][nt] = (f32x4){0.f, 0.f, 0.f, 0.f};

    auto stage = [&](int k0, int b) {
#pragma unroll
        for (int j = 0; j < 2; ++j) {
            int idx = j * 256 + t;
            int r = idx >> 3, c8 = idx & 7;
            int sc = c8 ^ (r & 7);
            async_cp16(A + (size_t)(m0 + r) * K + k0 + sc * 8, abuf[b] + idx * 8);
        }
#pragma unroll
        for (int j = 0; j < 4; ++j) {
            int idx = j * 256 + t;
            int r = idx >> 3, c8 = idx & 7;
            int sc = c8 ^ (r & 7);
            async_cp16(Bt + (size_t)(n0 + r) * K + k0 + sc * 8, bbuf[b] + idx * 8);
        }
    };

    const int nit = K >> 6;
    stage(0, 0);
    for (int i = 0; i < nit; ++i) {
        __syncthreads();              // vmcnt drained: tile i ready
        if (i + 1 < nit) stage((i + 1) << 6, (i + 1) & 1);
        const u16* ab = abuf[i & 1];
        const u16* bb = bbuf[i & 1];
#pragma unroll
        for (int kd = 0; kd < 2; ++kd) {
            short8 afr[2], bfr[4];
#pragma unroll
            for (int mt = 0; mt < 2; ++mt) {
                int ar = rh + mt * 16 + l;
                afr[mt] = *(const short8*)(ab + ar * 64 + (((kd * 4 + Q) ^ (ar & 7))) * 8);
            }
#pragma unroll
            for (int nt = 0; nt < 4; ++nt) {
                int br = ch + nt * 16 + l;
                bfr[nt] = *(const short8*)(bb + br * 64 + (((kd * 4 + Q) ^ (br & 7))) * 8);
            }
#pragma unroll
            for (int mt = 0; mt < 2; ++mt)
#pragma unroll
                for (int nt = 0; nt < 4; ++nt)
                    acc[mt][nt] = __builtin_amdgcn_mfma_f32_16x16x32_bf16(afr[mt], bfr[nt], acc[mt][nt], 0, 0, 0);
        }
    }

#pragma unroll
    for (int mt = 0; mt < 2; ++mt)
#pragma unroll
        for (int nt = 0; nt < 4; ++nt) {
            int col = n0 + ch + nt * 16 + l;
            int row0 = m0 + rh + mt * 16 + Q * 4;
            if (EPI == 0) {
                float b = bias[col];
                if (col < 512) {
#pragma unroll
                    for (int r = 0; r < 4; ++r)
                        out_bf[(size_t)(row0 + r) * 512 + col] = f2bf(acc[mt][nt][r] + b);
                } else {
                    ushort4 pk;
                    pk.x = f2bf(acc[mt][nt][0] + b);
                    pk.y = f2bf(acc[mt][nt][1] + b);
                    pk.z = f2bf(acc[mt][nt][2] + b);
                    pk.w = f2bf(acc[mt][nt][3] + b);
                    *(ushort4*)(out_vt + (size_t)(col - 512) * 8192 + row0) = pk;
                }
            } else {
#pragma unroll
                for (int r = 0; r < 4; ++r) {
                    float val = acc[mt][nt][r];
                    float gl = 0.5f * val * (1.f + erff(val * 0.70710678118654752f));
                    out_bf[(size_t)(row0 + r) * N + col] = f2bf(gl);
                }
            }
        }
}

// ---------------------------------------------------------------------------
// 64x64-tile double-buffered GEMM (kept for FFN2). EPI 3: +resid->f32
// ---------------------------------------------------------------------------
__global__ __launch_bounds__(256) void gemm64_res(
        const u16* __restrict__ A, const u16* __restrict__ Bt,
        int M, int N, int K,
        const float* __restrict__ resid, float* __restrict__ out_f32) {
    __shared__ u16 abuf[2][4096];
    __shared__ u16 bbuf[2][4096];
    const int t = threadIdx.x;
    const int w = t >> 6, lane = t & 63;
    const int l = lane & 15, Q = lane >> 4;
    const int m0 = blockIdx.x * 64;
    const int n0 = blockIdx.y * 64;

    f32x4 acc[4];
#pragma unroll
    for (int nt = 0; nt < 4; ++nt) acc[nt] = (f32x4){0.f, 0.f, 0.f, 0.f};

    auto stage = [&](int k0, int b) {
#pragma unroll
        for (int j = 0; j < 2; ++j) {
            int idx = j * 256 + t;
            int r = idx >> 3, c8 = idx & 7;
            int sc = c8 ^ (r & 7);
            async_cp16(A + (size_t)(m0 + r) * K + k0 + sc * 8, abuf[b] + idx * 8);
        }
#pragma unroll
        for (int j = 0; j < 2; ++j) {
            int idx = j * 256 + t;
            int r = idx >> 3, c8 = idx & 7;
            int sc = c8 ^ (r & 7);
            async_cp16(Bt + (size_t)(n0 + r) * K + k0 + sc * 8, bbuf[b] + idx * 8);
        }
    };

    const int nit = K >> 6;
    stage(0, 0);
    for (int i = 0; i < nit; ++i) {
        __syncthreads();
        if (i + 1 < nit) stage((i + 1) << 6, (i + 1) & 1);
        const u16* ab = abuf[i & 1];
        const u16* bb = bbuf[i & 1];
#pragma unroll
        for (int kd = 0; kd < 2; ++kd) {
            int ar = w * 16 + l;
            short8 afr = *(const short8*)(ab + ar * 64 + (((kd * 4 + Q) ^ (ar & 7))) * 8);
#pragma unroll
            for (int nt = 0; nt < 4; ++nt) {
                int r = nt * 16 + l;
                short8 bfr = *(const short8*)(bb + r * 64 + (((kd * 4 + Q) ^ (r & 7))) * 8);
                acc[nt] = __builtin_amdgcn_mfma_f32_16x16x32_bf16(afr, bfr, acc[nt], 0, 0, 0);
            }
        }
    }

#pragma unroll
    for (int nt = 0; nt < 4; ++nt) {
        int col = n0 + nt * 16 + l;
        int row0 = m0 + w * 16 + Q * 4;
#pragma unroll
        for (int r = 0; r < 4; ++r) {
            size_t oidx = (size_t)(row0 + r) * N + col;
            out_f32[oidx] = acc[nt][r] + resid[oidx];
        }
    }
}

// ---------------------------------------------------------------------------
// O-proj with FUSED combine (unchanged from R13).
// ---------------------------------------------------------------------------
__global__ __launch_bounds__(256) void gemm_oproj(
        const u16* __restrict__ opart, const float* __restrict__ lpart,
        const u16* __restrict__ Bt,
        const float* __restrict__ bias, const float* __restrict__ resid,
        float* __restrict__ out_f32, u16* __restrict__ out_bf,
        const float* __restrict__ b2sc, const float* __restrict__ b2sh) {
    __shared__ u16 abuf[4096];        // single-buffered combined-A (8 KB)
    __shared__ u16 bbuf[2][4096];
    const int t = threadIdx.x;
    const int w = t >> 6, lane = t & 63;
    const int l = lane & 15, Q = lane >> 4;
    const int m0 = blockIdx.x * 64;
    const int n0 = blockIdx.y * 64;
    const size_t SPSTR = (size_t)16 * 2048 * 64;   // opart sp stride (elems)

    f32x4 acc[4];
#pragma unroll
    for (int nt = 0; nt < 4; ++nt) acc[nt] = (f32x4){0.f, 0.f, 0.f, 0.f};

    auto stageB = [&](int k0, int b) {
#pragma unroll
        for (int j = 0; j < 2; ++j) {
            int idx = j * 256 + t;
            int r = idx >> 3, c8 = idx & 7;
            int sc = c8 ^ (r & 7);
            async_cp16(Bt + (size_t)(n0 + r) * 256 + k0 + sc * 8, bbuf[b] + idx * 8);
        }
    };

    stageB(0, 0);
    for (int i = 0; i < 4; ++i) {     // k0 = i*64, head hd = i
        uint4 aw[2];
#pragma unroll
        for (int j = 0; j < 2; ++j) {
            int idx = j * 256 + t;
            int r = idx >> 3, c8 = idx & 7;
            int dc = c8 ^ (r & 7);            // global d-chunk stored in this slot
            int row = m0 + r;
            int bh = (row >> 11) * 4 + i;
            int q = row & 2047;
            size_t lb = (size_t)bh * 2048 + q;
            float ls = lpart[lb] + lpart[lb + 32768] + lpart[lb + 65536] + lpart[lb + 98304];
            float inv = 1.0f / ls;
            size_t base = ((size_t)bh * 2048 + q) * 64 + dc * 8;
            uint4 v0 = *(const uint4*)(opart + base);
            uint4 v1 = *(const uint4*)(opart + SPSTR + base);
            uint4 v2 = *(const uint4*)(opart + 2 * SPSTR + base);
            uint4 v3 = *(const uint4*)(opart + 3 * SPSTR + base);
            u32 o[4];
            const u32* p0 = &v0.x; const u32* p1 = &v1.x;
            const u32* p2 = &v2.x; const u32* p3 = &v3.x;
#pragma unroll
            for (int e = 0; e < 4; ++e) {
                float lo = __uint_as_float(p0[e] << 16) + __uint_as_float(p1[e] << 16)
                         + __uint_as_float(p2[e] << 16) + __uint_as_float(p3[e] << 16);
                float hi = __uint_as_float(p0[e] & 0xffff0000u) + __uint_as_float(p1[e] & 0xffff0000u)
                         + __uint_as_float(p2[e] & 0xffff0000u) + __uint_as_float(p3[e] & 0xffff0000u);
                o[e] = (u32)f2bf(lo * inv) | ((u32)f2bf(hi * inv) << 16);
            }
            aw[j] = make_uint4(o[0], o[1], o[2], o[3]);
        }
        __syncthreads();              // prev compute done reading abuf; B[i] drained
#pragma unroll
        for (int j = 0; j < 2; ++j)
            *(uint4*)(abuf + ((size_t)(j * 256 + t)) * 8) = aw[j];
        if (i < 3) stageB((i + 1) * 64, (i + 1) & 1);
        __syncthreads();              // abuf visible to all waves
        const u16* bb = bbuf[i & 1];
#pragma unroll
        for (int kd = 0; kd < 2; ++kd) {
            int ar = w * 16 + l;
            short8 afr = *(const short8*)(abuf + ar * 64 + (((kd * 4 + Q) ^ (ar & 7))) * 8);
#pragma unroll
            for (int nt = 0; nt < 4; ++nt) {
                int r = nt * 16 + l;
                short8 bfr = *(const short8*)(bb + r * 64 + (((kd * 4 + Q) ^ (r & 7))) * 8);
                acc[nt] = __builtin_amdgcn_mfma_f32_16x16x32_bf16(afr, bfr, acc[nt], 0, 0, 0);
            }
        }
    }

#pragma unroll
    for (int nt = 0; nt < 4; ++nt) {
        int col = n0 + nt * 16 + l;
        int row0 = m0 + w * 16 + Q * 4;
#pragma unroll
        for (int r = 0; r < 4; ++r) {
            size_t oidx = (size_t)(row0 + r) * 256 + col;
            float val = acc[nt][r] + bias[col] + resid[oidx];
            out_f32[oidx] = val;
            out_bf[oidx] = f2bf(fmaf(val, b2sc[col], b2sh[col]));
        }
    }
}

// ---------------------------------------------------------------------------
// Flash attention v9: sp=4 kept (low partial traffic), qt split 16->32 so
// grid = 2048 (8 WG/CU, up to 32 waves/CU). WG = 64 q rows, wave = 16 rows
// (qg eliminated -> fewer VGPRs). Single-buffered 16 KB K/V LDS (2 barriers
// per iter; inter-WG overlap hides the stage). 1D grid blk = qt*64 + sp*16
// + bh (64 % 8 == 0 preserves per-XCD K/V L2 reuse). l via ones-row MFMA.
// ---------------------------------------------------------------------------
static __device__ __forceinline__ void stage_tiles(const u16* kglob, const u16* vglob,
                                                   u16* kdst, u16* vdst,
                                                   int w, int lane, int kt) {
#pragma unroll
    for (int j = 0; j < 2; ++j) {
        int cw = (w * 2 + j) * 64 + lane;     // chunk 0..511
        int r = cw >> 3;                       // tile row 0..63
        int c = (cw & 7) ^ (r & 7);            // swizzled source chunk
        async_cp16(kglob + ((size_t)(kt * 64 + r)) * 512 + c * 8, kdst + (w * 2 + j) * 512);
        async_cp16(vglob + ((size_t)r) * 8192 + kt * 64 + c * 8, vdst + (w * 2 + j) * 512);
    }
}

__global__ __launch_bounds__(256) void attn_kernel(const u16* __restrict__ qk,
                                                   const u16* __restrict__ vT,
                                                   u16* __restrict__ opart,
                                                   float* __restrict__ lpart) {
    __shared__ u16 kbuf[4096];
    __shared__ u16 vbuf[4096];
    const int t = threadIdx.x;
    const int w = t >> 6, lane = t & 63;
    const int l = lane & 15, Q = lane >> 4;
    const int blk = blockIdx.x;
    const int qt = blk >> 6;          // 0..31  (slowest: XCD-local K/V reuse)
    const int sp = (blk >> 4) & 3;    // 0..3   (512 s each)
    const int bh = blk & 15;          // 0..15
    const int bb = bh >> 2, hd = bh & 3;
    const size_t rowbase = (size_t)bb * 2048;
    const int q0 = qt * 64 + w * 16;

    short8 qf[2];
#pragma unroll
    for (int kd = 0; kd < 2; ++kd)
        qf[kd] = *(const short8*)(qk + (rowbase + q0 + l) * 512
                                  + hd * 64 + kd * 32 + Q * 8);

    f32x4 o[4];
#pragma unroll
    for (int dt = 0; dt < 4; ++dt) o[dt] = (f32x4){0.f, 0.f, 0.f, 0.f};
    f32x4 oL = (f32x4){0.f, 0.f, 0.f, 0.f};   // l accumulator via ones-MFMA
    union { u32 u[2]; short4v s4; } ones;
    ones.u[0] = 0x3F803F80u; ones.u[1] = 0x3F803F80u;   // bf16 1.0 x4

    const u16* kglob = qk + (rowbase + sp * 512) * 512 + 256 + hd * 64;
    const u16* vglob = vT + ((size_t)(hd * 64)) * 8192 + rowbase + sp * 512;

    for (int kt = 0; kt < 8; ++kt) {
        stage_tiles(kglob, vglob, kbuf, vbuf, w, lane, kt);
        __syncthreads();              // drains vmcnt: tile ready

        union { u32 u[2]; short4v s4; } pf[4];
#pragma unroll
        for (int st = 0; st < 4; ++st) {
            int r = st * 16 + l;
            short8 kf0 = *(const short8*)(kbuf + r * 64 + ((Q) ^ (r & 7)) * 8);
            short8 kf1 = *(const short8*)(kbuf + r * 64 + ((4 + Q) ^ (r & 7)) * 8);
            f32x4 s = (f32x4){0.f, 0.f, 0.f, 0.f};
            s = __builtin_amdgcn_mfma_f32_16x16x32_bf16(kf0, qf[0], s, 0, 0, 0);
            s = __builtin_amdgcn_mfma_f32_16x16x32_bf16(kf1, qf[1], s, 0, 0, 0);
            float p0 = EXP2F(s[0]);
            float p1 = EXP2F(s[1]);
            float p2 = EXP2F(s[2]);
            float p3 = EXP2F(s[3]);
            pf[st].u[0] = pack_bf2_trunc(p0, p1);
            pf[st].u[1] = pack_bf2_trunc(p2, p3);
        }

#pragma unroll
        for (int c = 0; c < 4; ++c) {
#pragma unroll
            for (int dt = 0; dt < 4; ++dt) {
                int r = dt * 16 + l;
                int slot = (2 * c + (Q >> 1)) ^ (r & 7);
                short4v vf = *(const short4v*)(vbuf + r * 64 + slot * 8 + (Q & 1) * 4);
                o[dt] = MFMA16(vf, pf[c].s4, o[dt]);
            }
            oL = MFMA16(ones.s4, pf[c].s4, oL);
        }
        __syncthreads();              // all waves done before restage
    }

    // epilogue: bf16 partials; l = oL[0] (each col q holds its sum)
    u16* ob = opart + (((size_t)sp * 16 + bh) * 2048 + q0) * 64;
#pragma unroll
    for (int dt = 0; dt < 4; ++dt) {
        ushort4 pk;
        pk.x = f2bf(o[dt][0]);
        pk.y = f2bf(o[dt][1]);
        pk.z = f2bf(o[dt][2]);
        pk.w = f2bf(o[dt][3]);
        *(ushort4*)(ob + (size_t)l * 64 + dt * 16 + Q * 4) = pk;
    }
    if (Q == 0) {
        size_t lb = ((size_t)sp * 16 + bh) * 2048 + q0;
        lpart[lb + l] = oL[0];
    }
}

// ---------------------------------------------------------------------------
extern "C" void kernel_launch(void* const* d_in, const int* in_sizes, int n_in,
                              void* d_out, int out_size, void* d_ws, size_t ws_size,
                              hipStream_t stream) {
    (void)in_sizes; (void)n_in; (void)out_size; (void)ws_size;
    const float* x  = (const float*)d_in[0];
    const float* g1 = (const float*)d_in[1];
    const float* b1 = (const float*)d_in[2];
    const float* m1 = (const float*)d_in[3];
    const float* v1 = (const float*)d_in[4];
    const float* wq = (const float*)d_in[5];
    const float* bq = (const float*)d_in[6];
    const float* wk = (const float*)d_in[7];
    const float* bk = (const float*)d_in[8];
    const float* wv = (const float*)d_in[9];
    const float* bv = (const float*)d_in[10];
    const float* wo = (const float*)d_in[11];
    const float* bo = (const float*)d_in[12];
    const float* g2 = (const float*)d_in[13];
    const float* b2 = (const float*)d_in[14];
    const float* m2 = (const float*)d_in[15];
    const float* v2 = (const float*)d_in[16];
    const float* w1 = (const float*)d_in[17];
    const float* w2 = (const float*)d_in[18];

    char* ws = (char*)d_ws;
    u16*   qkb    = (u16*)(ws + (0ull << 20));    // [8192][512] bf16, 8 MB
    u16*   vTb    = (u16*)(ws + (8ull << 20));    // [256][8192] bf16, 4 MB
    u16*   h_buf  = (u16*)(ws + (12ull << 20));   // [8192][256] bf16, 4 MB
    float* x1     = (float*)(ws + (20ull << 20)); // [8192][256] f32, 8 MB
    u16*   h2     = (u16*)(ws + (28ull << 20));   // [8192][256] bf16, 4 MB
    u16*   gbuf   = (u16*)(ws + (32ull << 20));   // [8192][1024] bf16, 16 MB
    u16*   opart  = (u16*)(ws + (48ull << 20));   // [4][16][2048][64] bf16, 16 MB
    float* lpart  = (float*)(ws + (80ull << 20)); // [4][16][2048] f32, 512 KB
    u16*   wqkvT  = (u16*)(ws + (81ull << 20));   // [768][256] bf16
    u16*   woT    = (u16*)(ws + (82ull << 20));   // [256][256]
    u16*   w1T    = (u16*)(ws + (83ull << 20));   // [1024][256]
    u16*   w2T    = (u16*)(ws + (84ull << 20));   // [256][1024]
    float* bqkv   = (float*)(ws + (85ull << 20)); // [768]
    float* bn2sc  = (float*)(ws + (85ull << 20) + 4096);
    float* bn2sh  = (float*)(ws + (85ull << 20) + 8192);
    float* out    = (float*)d_out;

    prep_bn1_kernel<<<5125, 256, 0, stream>>>(x, wq, wk, wv, wo, w1, w2, bq, bk, bv,
                                              g1, b1, m1, v1, g2, b2, m2, v2,
                                              h_buf, wqkvT, woT, w1T, w2T, bqkv,
                                              bn2sc, bn2sh);
    // QKV projection, 64x128 tiles (q|k row-major into qkb; v transposed into vTb)
    gemm128<0><<<dim3(128, 6), 256, 0, stream>>>(
        h_buf, wqkvT, 8192, 768, 256, bqkv, qkb, vTb);
    // attention partials (1D grid, qt slowest for XCD L2 reuse; 8 WG/CU)
    attn_kernel<<<2048, 256, 0, stream>>>(qkb, vTb, opart, lpart);
    // O projection with fused combine + residual + bn2
    gemm_oproj<<<dim3(128, 4), 256, 0, stream>>>(
        opart, lpart, woT, bo, x, x1, h2, bn2sc, bn2sh);
    // FFN1 + gelu, 64x128 tiles
    gemm128<2><<<dim3(128, 8), 256, 0, stream>>>(
        h2, w1T, 8192, 1024, 256, nullptr, gbuf, nullptr);
    // FFN2 + residual -> out
    gemm64_res<<<dim3(128, 4), 256, 0, stream>>>(
        gbuf, w2T, 8192, 256, 1024, x1, out);
}